// Round 1
// baseline (535.426 us; speedup 1.0000x reference)
//
#include <hip/hip_runtime.h>

#define NODE_NUM 2000
#define DM 2048          // D_MODEL, also padded K/N
#define IN_DIM 7
#define CONV_CH 64
#define KER 49
#define BATCH 64

typedef __attribute__((ext_vector_type(8))) short bf16x8;
typedef __attribute__((ext_vector_type(4))) float f32x4;
typedef __attribute__((ext_vector_type(4))) unsigned int u32x4;

__device__ __forceinline__ float bf2f(unsigned short u) {
  union { unsigned int i; float f; } c; c.i = ((unsigned int)u) << 16; return c.f;
}
__device__ __forceinline__ unsigned short f2bf(float f) {
  union { float f; unsigned int i; } c; c.f = f;
  unsigned int r = c.i + 0x7FFFu + ((c.i >> 16) & 1u);
  return (unsigned short)(r >> 16);
}

// ---------------------------------------------------------------------------
// Adjacency: a[v][w] = (softmax_w(relu(nv1[v]·nv2[:,w])) + (v==w)) / 2
// Stored bf16, padded to [2048][2048] with zeros. Row-major over w = Bt layout.
// ---------------------------------------------------------------------------
__global__ __launch_bounds__(256) void adj_kernel(const float* __restrict__ nv1,
                                                  const float* __restrict__ nv2,
                                                  unsigned short* __restrict__ Ab) {
  const int v = blockIdx.x;
  const int tid = threadIdx.x;
  if (v >= NODE_NUM) {
    for (int w = tid; w < DM; w += 256) Ab[(size_t)v * DM + w] = 0;
    return;
  }
  __shared__ float e1[40];
  __shared__ float rmax[4], rsum[4];
  if (tid < 40) e1[tid] = nv1[v * 40 + tid];
  __syncthreads();
  float s[8];
  float mx = 0.f;
#pragma unroll
  for (int i = 0; i < 8; ++i) {
    const int w = i * 256 + tid;
    float acc = -1e30f;
    if (w < NODE_NUM) {
      acc = 0.f;
#pragma unroll
      for (int k = 0; k < 40; ++k) acc += e1[k] * nv2[k * NODE_NUM + w];
      acc = fmaxf(acc, 0.f);
    }
    s[i] = acc;
    mx = fmaxf(mx, acc);
  }
  for (int o = 32; o; o >>= 1) mx = fmaxf(mx, __shfl_xor(mx, o));
  const int wid = tid >> 6, lane = tid & 63;
  if (lane == 0) rmax[wid] = mx;
  __syncthreads();
  mx = fmaxf(fmaxf(rmax[0], rmax[1]), fmaxf(rmax[2], rmax[3]));
  float sum = 0.f;
#pragma unroll
  for (int i = 0; i < 8; ++i) {
    const int w = i * 256 + tid;
    const float e = (w < NODE_NUM) ? __expf(s[i] - mx) : 0.f;
    s[i] = e; sum += e;
  }
  for (int o = 32; o; o >>= 1) sum += __shfl_xor(sum, o);
  if (lane == 0) rsum[wid] = sum;
  __syncthreads();
  sum = rsum[0] + rsum[1] + rsum[2] + rsum[3];
  const float inv = 0.5f / sum;
#pragma unroll
  for (int i = 0; i < 8; ++i) {
    const int w = i * 256 + tid;
    const float val = s[i] * inv + ((w == v) ? 0.5f : 0.f);
    Ab[(size_t)v * DM + w] = f2bf(val);  // w>=2000 has s[i]=0 -> writes 0
  }
}

// ---------------------------------------------------------------------------
// Start conv: h0[b*64+c][n] = b_start[c] + sum_{ci,k} x[b][ci][n+k]*w[c][ci][k]
// Output bf16 [4096][2048], cols >= 2000 zeroed.
// ---------------------------------------------------------------------------
__global__ __launch_bounds__(256) void conv_kernel(const float* __restrict__ x,
                                                   const float* __restrict__ wst,
                                                   const float* __restrict__ bst,
                                                   unsigned short* __restrict__ H0) {
  __shared__ unsigned short wl[CONV_CH * IN_DIM * KER];  // 43904 B bf16
  __shared__ float xs[IN_DIM][116];
  const int b = blockIdx.y;
  const int n0 = blockIdx.x * 64;
  const int tid = threadIdx.x;
  for (int i = tid; i < CONV_CH * IN_DIM * KER; i += 256) wl[i] = f2bf(wst[i]);
  for (int i = tid; i < IN_DIM * 113; i += 256) {
    const int ci = i / 113, p = i % 113;
    const int gx = n0 + p;
    xs[ci][p] = (gx < DM) ? x[(size_t)b * (IN_DIM * DM) + ci * DM + gx] : 0.f;
  }
  __syncthreads();
  const int c = tid >> 2, j = tid & 3;
  float acc[16];
  const float bv = bst[c];
#pragma unroll
  for (int i = 0; i < 16; ++i) acc[i] = bv;
  for (int ci = 0; ci < IN_DIM; ++ci) {
    float buf[16];
#pragma unroll
    for (int i = 0; i < 16; ++i) buf[i] = xs[ci][j * 16 + i];
#pragma unroll
    for (int k = 0; k < KER; ++k) {
      const float wv = bf2f(wl[c * (IN_DIM * KER) + ci * KER + k]);
#pragma unroll
      for (int nn = 0; nn < 16; ++nn) acc[nn] += wv * buf[(k + nn) & 15];
      if (k < 48) buf[k & 15] = xs[ci][j * 16 + k + 16];
    }
  }
  const size_t m = (size_t)(b * 64 + c) * DM;
#pragma unroll
  for (int nn = 0; nn < 16; ++nn) {
    const int n = n0 + j * 16 + nn;
    H0[m + n] = (n < NODE_NUM) ? f2bf(acc[nn]) : (unsigned short)0;
  }
}

// ---------------------------------------------------------------------------
// NT-GEMM: C[m][n] = sum_k A[m][k] * Bt[n][k], lda=ldb=ldc=2048, K=2048.
// 128x128 tile, BK=64, 4 waves (2x2), 16x16x32 bf16 MFMA, XOR-swizzled LDS
// fed by global_load_lds with pre-swizzled source addresses.
// MODE 0: mixprop epilogue  out = bf16(0.05*H0 + 0.95*acc)
// MODE 1: final             out = f32 acc, rows < 64 only
// ---------------------------------------------------------------------------
template <int MODE>
__global__ __launch_bounds__(256) void gemm_nt(const unsigned short* __restrict__ A,
                                               const unsigned short* __restrict__ Bt,
                                               const unsigned short* __restrict__ H0,
                                               void* __restrict__ Cout) {
  __shared__ alignas(16) unsigned short As[128 * 64];
  __shared__ alignas(16) unsigned short Bs[128 * 64];
  const int tid = threadIdx.x;
  const int m0 = blockIdx.y * 128, n0 = blockIdx.x * 128;
  const int wid = tid >> 6, lane = tid & 63;
  const int wr = wid >> 1, wc = wid & 1;
  const int l15 = lane & 15, kg = lane >> 4;
  f32x4 acc[4][4] = {};
  for (int k0 = 0; k0 < DM; k0 += 64) {
#pragma unroll
    for (int it = 0; it < 4; ++it) {
      const int lin = it * 4096 + tid * 16;              // linear byte in 16KB tile
      const int row = lin >> 7;                          // 128B per row (64 bf16)
      const int blog = (lin & 127) ^ ((row & 7) << 4);   // inverse swizzle -> logical
      const char* sa = (const char*)A + ((size_t)(m0 + row) * DM + k0) * 2 + blog;
      const char* sb = (const char*)Bt + ((size_t)(n0 + row) * DM + k0) * 2 + blog;
      __builtin_amdgcn_global_load_lds((const __attribute__((address_space(1))) void*)sa,
                                       (__attribute__((address_space(3))) void*)((char*)As + lin),
                                       16, 0, 0);
      __builtin_amdgcn_global_load_lds((const __attribute__((address_space(1))) void*)sb,
                                       (__attribute__((address_space(3))) void*)((char*)Bs + lin),
                                       16, 0, 0);
    }
    __syncthreads();
    bf16x8 af[2][4], bfr[2][4];
#pragma unroll
    for (int f = 0; f < 4; ++f) {
      const int ra = wr * 64 + f * 16 + l15;
      const int rb = wc * 64 + f * 16 + l15;
#pragma unroll
      for (int kk = 0; kk < 2; ++kk) {
        const int off = kk * 64 + kg * 16;
        af[kk][f]  = *(const bf16x8*)((const char*)As + ra * 128 + (off ^ ((ra & 7) << 4)));
        bfr[kk][f] = *(const bf16x8*)((const char*)Bs + rb * 128 + (off ^ ((rb & 7) << 4)));
      }
    }
#pragma unroll
    for (int kk = 0; kk < 2; ++kk)
#pragma unroll
      for (int mf = 0; mf < 4; ++mf)
#pragma unroll
        for (int nf = 0; nf < 4; ++nf)
          acc[mf][nf] = __builtin_amdgcn_mfma_f32_16x16x32_bf16(af[kk][mf], bfr[kk][nf],
                                                                acc[mf][nf], 0, 0, 0);
    __syncthreads();
  }
  const int l4 = lane >> 4;
#pragma unroll
  for (int mf = 0; mf < 4; ++mf) {
#pragma unroll
    for (int nf = 0; nf < 4; ++nf) {
#pragma unroll
      for (int r = 0; r < 4; ++r) {
        const int gm = m0 + wr * 64 + mf * 16 + l4 * 4 + r;
        const int gn = n0 + wc * 64 + nf * 16 + l15;
        if (MODE == 0) {
          const float v = 0.05f * bf2f(H0[(size_t)gm * DM + gn]) + 0.95f * acc[mf][nf][r];
          ((unsigned short*)Cout)[(size_t)gm * DM + gn] = f2bf(v);
        } else {
          if (gm < 64) ((float*)Cout)[(size_t)gm * DM + gn] = acc[mf][nf][r];
        }
      }
    }
  }
}

// ---------------------------------------------------------------------------
// MLP (1x1 conv 256->64) + bias + exact gelu + w_end reduce -> out1[b][n] bf16
// ---------------------------------------------------------------------------
__global__ __launch_bounds__(256) void mlp_kernel(const unsigned short* __restrict__ h0,
                                                  const unsigned short* __restrict__ h1,
                                                  const unsigned short* __restrict__ h2,
                                                  const unsigned short* __restrict__ h3,
                                                  const float* __restrict__ wm,
                                                  const float* __restrict__ bm,
                                                  const float* __restrict__ we,
                                                  const float* __restrict__ be,
                                                  unsigned short* __restrict__ out1) {
  __shared__ alignas(16) unsigned short hs[256][64];
  __shared__ float red[4][64];
  const int b = blockIdx.y;
  const int n0 = blockIdx.x * 64;
  const int tid = threadIdx.x;
#pragma unroll
  for (int ch = tid; ch < 2048; ch += 256) {  // 2048 chunks of 8 bf16
    const int cf = ch >> 3;
    const int co = (ch & 7) * 8;
    const int hop = cf >> 6, c = cf & 63;
    const unsigned short* hb = (hop == 0) ? h0 : (hop == 1) ? h1 : (hop == 2) ? h2 : h3;
    const unsigned short* src = hb + (size_t)(b * 64 + c) * DM + n0 + co;
    *(u32x4*)&hs[cf][co] = *(const u32x4*)src;
  }
  __syncthreads();
  const int n = tid & 63;
  const int ob = __builtin_amdgcn_readfirstlane((tid >> 6) * 16);
  float acc[16] = {};
  for (int cb = 0; cb < 256; cb += 4) {
    const float x0 = bf2f(hs[cb + 0][n]);
    const float x1 = bf2f(hs[cb + 1][n]);
    const float x2 = bf2f(hs[cb + 2][n]);
    const float x3 = bf2f(hs[cb + 3][n]);
#pragma unroll
    for (int o = 0; o < 16; ++o) {
      const float* wr = wm + (ob + o) * 256 + cb;   // wave-uniform -> s_load
      acc[o] += wr[0] * x0 + wr[1] * x1 + wr[2] * x2 + wr[3] * x3;
    }
  }
  float part = 0.f;
#pragma unroll
  for (int o = 0; o < 16; ++o) {
    const float sv = acc[o] + bm[ob + o];
    const float g = 0.5f * sv * (1.f + erff(sv * 0.70710678118f));
    part += we[ob + o] * g;
  }
  const int og = tid >> 6;
  red[og][n] = part;
  __syncthreads();
  if (og == 0) {
    const float tot = red[0][n] + red[1][n] + red[2][n] + red[3][n] + be[0];
    const int gn = n0 + n;
    out1[(size_t)b * DM + gn] = (gn < NODE_NUM) ? f2bf(tot) : (unsigned short)0;
  }
}

// ---------------------------------------------------------------------------
// w_lin (2048 x 2000 f32) -> bf16 [2048][2048], pad cols zeroed
// ---------------------------------------------------------------------------
__global__ __launch_bounds__(256) void wlin_cvt(const float* __restrict__ wlin,
                                                unsigned short* __restrict__ wl) {
  const int idx = blockIdx.x * 256 + threadIdx.x;
  const int d = idx >> 11, w = idx & 2047;
  wl[idx] = (w < NODE_NUM) ? f2bf(wlin[d * NODE_NUM + w]) : (unsigned short)0;
}

// ---------------------------------------------------------------------------
// +b_lin then LayerNorm over 2048, f32 out
// ---------------------------------------------------------------------------
__global__ __launch_bounds__(256) void ln_kernel(const float* __restrict__ y,
                                                 const float* __restrict__ bl,
                                                 const float* __restrict__ g,
                                                 const float* __restrict__ bb,
                                                 float* __restrict__ out) {
  const int b = blockIdx.x, tid = threadIdx.x;
  __shared__ float rs[4], rq[4];
  float v[8];
  float s = 0.f;
#pragma unroll
  for (int i = 0; i < 8; ++i) {
    const int d = i * 256 + tid;
    v[i] = y[(size_t)b * DM + d] + bl[d];
    s += v[i];
  }
  for (int o = 32; o; o >>= 1) s += __shfl_xor(s, o);
  const int wid = tid >> 6, lane = tid & 63;
  if (lane == 0) rs[wid] = s;
  __syncthreads();
  s = rs[0] + rs[1] + rs[2] + rs[3];
  const float mu = s * (1.f / 2048.f);
  float q = 0.f;
#pragma unroll
  for (int i = 0; i < 8; ++i) { const float d = v[i] - mu; q += d * d; }
  for (int o = 32; o; o >>= 1) q += __shfl_xor(q, o);
  if (lane == 0) rq[wid] = q;
  __syncthreads();
  q = rq[0] + rq[1] + rq[2] + rq[3];
  const float inv = rsqrtf(q * (1.f / 2048.f) + 1e-5f);
#pragma unroll
  for (int i = 0; i < 8; ++i) {
    const int d = i * 256 + tid;
    out[(size_t)b * DM + d] = (v[i] - mu) * inv * g[d] + bb[d];
  }
}

// ---------------------------------------------------------------------------
extern "C" void kernel_launch(void* const* d_in, const int* in_sizes, int n_in,
                              void* d_out, int out_size, void* d_ws, size_t ws_size,
                              hipStream_t stream) {
  const float* x      = (const float*)d_in[0];
  const float* nv1    = (const float*)d_in[1];
  const float* nv2    = (const float*)d_in[2];
  const float* w_st   = (const float*)d_in[3];
  const float* b_st   = (const float*)d_in[4];
  const float* w_mlp  = (const float*)d_in[5];
  const float* b_mlp  = (const float*)d_in[6];
  const float* w_end  = (const float*)d_in[7];
  const float* b_end  = (const float*)d_in[8];
  const float* w_lin  = (const float*)d_in[9];
  const float* b_lin  = (const float*)d_in[10];
  const float* ln_g   = (const float*)d_in[11];
  const float* ln_b   = (const float*)d_in[12];

  char* ws = (char*)d_ws;
  const size_t SZ_A  = (size_t)DM * DM * 2;        // 8 MB
  const size_t SZ_H  = (size_t)4096 * DM * 2;      // 16 MB
  unsigned short* Ab   = (unsigned short*)(ws);
  unsigned short* H0   = (unsigned short*)(ws + SZ_A);
  unsigned short* H1   = (unsigned short*)(ws + SZ_A + SZ_H);
  unsigned short* H2   = (unsigned short*)(ws + SZ_A + 2 * SZ_H);
  unsigned short* H3   = (unsigned short*)(ws + SZ_A + 3 * SZ_H);
  unsigned short* OUT1 = (unsigned short*)(ws + SZ_A + 4 * SZ_H);            // [128][2048]
  unsigned short* WL   = (unsigned short*)(ws + SZ_A + 4 * SZ_H + 524288);   // 8 MB
  float*          Y    = (float*)(ws + SZ_A + 4 * SZ_H + 524288 + SZ_A);     // [64][2048] f32

  adj_kernel<<<2048, 256, 0, stream>>>(nv1, nv2, Ab);
  conv_kernel<<<dim3(32, BATCH), 256, 0, stream>>>(x, w_st, b_st, H0);
  wlin_cvt<<<16384, 256, 0, stream>>>(w_lin, WL);

  gemm_nt<0><<<dim3(16, 32), 256, 0, stream>>>(H0, Ab, H0, (void*)H1);
  gemm_nt<0><<<dim3(16, 32), 256, 0, stream>>>(H1, Ab, H0, (void*)H2);
  gemm_nt<0><<<dim3(16, 32), 256, 0, stream>>>(H2, Ab, H0, (void*)H3);

  mlp_kernel<<<dim3(32, BATCH), 256, 0, stream>>>(H0, H1, H2, H3, w_mlp, b_mlp,
                                                  w_end, b_end, OUT1);
  gemm_nt<1><<<dim3(16, 1), 256, 0, stream>>>(OUT1, WL, (const unsigned short*)0, (void*)Y);
  ln_kernel<<<BATCH, 256, 0, stream>>>(Y, b_lin, ln_g, ln_b, (float*)d_out);
}

// Round 4
// 378.515 us; speedup vs baseline: 1.4145x; 1.4145x over previous
//
#include <hip/hip_runtime.h>

#define NODE_NUM 2000
#define DM 2048          // D_MODEL, also padded K/N
#define IN_DIM 7
#define CONV_CH 64
#define KER 49
#define BATCH 64

typedef __attribute__((ext_vector_type(8))) short bf16x8;
typedef __attribute__((ext_vector_type(4))) float f32x4;
typedef __attribute__((ext_vector_type(4))) unsigned int u32x4;

__device__ __forceinline__ float bf2f(unsigned short u) {
  union { unsigned int i; float f; } c; c.i = ((unsigned int)u) << 16; return c.f;
}
__device__ __forceinline__ unsigned short f2bf(float f) {
  union { float f; unsigned int i; } c; c.f = f;
  unsigned int r = c.i + 0x7FFFu + ((c.i >> 16) & 1u);
  return (unsigned short)(r >> 16);
}

// ---------------------------------------------------------------------------
// Adjacency: a[v][w] = (softmax_w(relu(nv1[v]·nv2[:,w])) + (v==w)) / 2
// 8 rows per block, acc[8][8] register tile: 64 FMA per 8 global loads.
// ---------------------------------------------------------------------------
__global__ __launch_bounds__(256) void adj_kernel(const float* __restrict__ nv1,
                                                  const float* __restrict__ nv2,
                                                  unsigned short* __restrict__ Ab) {
  const int bid = blockIdx.x;
  const int tid = threadIdx.x;
  if (bid >= 250) {  // zero pad rows 2000..2047
    const int r0 = 2000 + (bid - 250) * 8;
    for (int i = tid; i < 8 * 2048; i += 256)
      Ab[(size_t)(r0 + (i >> 11)) * DM + (i & 2047)] = 0;
    return;
  }
  const int v0 = bid * 8;
  __shared__ float e1s[8][40];
  __shared__ float redm[8][4], redsum[8][4];
  for (int i = tid; i < 320; i += 256) e1s[i / 40][i % 40] = nv1[(v0 + i / 40) * 40 + i % 40];
  __syncthreads();
  float acc[8][8] = {};
  for (int k = 0; k < 40; ++k) {
    float xv[8];
#pragma unroll
    for (int i = 0; i < 8; ++i) {
      const int w = i * 256 + tid;
      xv[i] = (w < NODE_NUM) ? nv2[k * NODE_NUM + w] : 0.f;
    }
#pragma unroll
    for (int v = 0; v < 8; ++v) {
      const float e = e1s[v][k];
#pragma unroll
      for (int i = 0; i < 8; ++i) acc[v][i] = fmaf(e, xv[i], acc[v][i]);
    }
  }
  const int wid = tid >> 6, lane = tid & 63;
#pragma unroll
  for (int v = 0; v < 8; ++v) {
    float mx = 0.f;
#pragma unroll
    for (int i = 0; i < 8; ++i) {
      const int w = i * 256 + tid;
      const float s = (w < NODE_NUM) ? fmaxf(acc[v][i], 0.f) : -1e30f;
      acc[v][i] = s; mx = fmaxf(mx, s);
    }
    for (int o = 32; o; o >>= 1) mx = fmaxf(mx, __shfl_xor(mx, o));
    if (lane == 0) redm[v][wid] = mx;
  }
  __syncthreads();
#pragma unroll
  for (int v = 0; v < 8; ++v) {
    const float mx = fmaxf(fmaxf(redm[v][0], redm[v][1]), fmaxf(redm[v][2], redm[v][3]));
    float sum = 0.f;
#pragma unroll
    for (int i = 0; i < 8; ++i) { const float e = __expf(acc[v][i] - mx); acc[v][i] = e; sum += e; }
    for (int o = 32; o; o >>= 1) sum += __shfl_xor(sum, o);
    if (lane == 0) redsum[v][wid] = sum;
  }
  __syncthreads();
#pragma unroll
  for (int v = 0; v < 8; ++v) {
    const float sum = redsum[v][0] + redsum[v][1] + redsum[v][2] + redsum[v][3];
    const float inv = 0.5f / sum;
    const int vg = v0 + v;
#pragma unroll
    for (int i = 0; i < 8; ++i) {
      const int w = i * 256 + tid;
      const float val = acc[v][i] * inv + ((w == vg) ? 0.5f : 0.f);
      Ab[(size_t)vg * DM + w] = f2bf(val);
    }
  }
}

// ---------------------------------------------------------------------------
// Start conv: h0[b*64+c][n] = b_start[c] + sum_{ci,k} x[b][ci][n+k]*w[c][ci][k]
// ---------------------------------------------------------------------------
__global__ __launch_bounds__(256) void conv_kernel(const float* __restrict__ x,
                                                   const float* __restrict__ wst,
                                                   const float* __restrict__ bst,
                                                   unsigned short* __restrict__ H0) {
  __shared__ unsigned short wl[CONV_CH * IN_DIM * KER];
  __shared__ float xs[IN_DIM][116];
  const int b = blockIdx.y;
  const int n0 = blockIdx.x * 64;
  const int tid = threadIdx.x;
  for (int i = tid; i < CONV_CH * IN_DIM * KER; i += 256) wl[i] = f2bf(wst[i]);
  for (int i = tid; i < IN_DIM * 113; i += 256) {
    const int ci = i / 113, p = i % 113;
    const int gx = n0 + p;
    xs[ci][p] = (gx < DM) ? x[(size_t)b * (IN_DIM * DM) + ci * DM + gx] : 0.f;
  }
  __syncthreads();
  const int c = tid >> 2, j = tid & 3;
  float acc[16];
  const float bv = bst[c];
#pragma unroll
  for (int i = 0; i < 16; ++i) acc[i] = bv;
  for (int ci = 0; ci < IN_DIM; ++ci) {
    float buf[16];
#pragma unroll
    for (int i = 0; i < 16; ++i) buf[i] = xs[ci][j * 16 + i];
#pragma unroll
    for (int k = 0; k < KER; ++k) {
      const float wv = bf2f(wl[c * (IN_DIM * KER) + ci * KER + k]);
#pragma unroll
      for (int nn = 0; nn < 16; ++nn) acc[nn] += wv * buf[(k + nn) & 15];
      if (k < 48) buf[k & 15] = xs[ci][j * 16 + k + 16];
    }
  }
  const size_t m = (size_t)(b * 64 + c) * DM;
#pragma unroll
  for (int nn = 0; nn < 16; ++nn) {
    const int n = n0 + j * 16 + nn;
    H0[m + n] = (n < NODE_NUM) ? f2bf(acc[nn]) : (unsigned short)0;
  }
}

// ---------------------------------------------------------------------------
// NT-GEMM: C[m][n] = sum_k A[m][k] * Bt[n][k], lda=ldb=ldc=2048.
// MODE 0: full K, mixprop epilogue  out = bf16(0.05*H0 + 0.95*acc)
// MODE 1: split-K (blockIdx.y = split of 256 k's), m0=0, f32 partial out
// ---------------------------------------------------------------------------
template <int MODE>
__global__ __launch_bounds__(256) void gemm_nt(const unsigned short* __restrict__ A,
                                               const unsigned short* __restrict__ Bt,
                                               const unsigned short* __restrict__ H0,
                                               void* __restrict__ Cout) {
  __shared__ alignas(16) unsigned short As[128 * 64];
  __shared__ alignas(16) unsigned short Bs[128 * 64];
  const int tid = threadIdx.x;
  const int n0 = blockIdx.x * 128;
  const int m0 = (MODE == 0) ? blockIdx.y * 128 : 0;
  const int kbeg = (MODE == 0) ? 0 : blockIdx.y * 256;
  const int kend = (MODE == 0) ? DM : kbeg + 256;
  const int wid = tid >> 6, lane = tid & 63;
  const int wr = wid >> 1, wc = wid & 1;
  const int l15 = lane & 15, kg = lane >> 4;
  f32x4 acc[4][4] = {};
  for (int k0 = kbeg; k0 < kend; k0 += 64) {
#pragma unroll
    for (int it = 0; it < 4; ++it) {
      const int lin = it * 4096 + tid * 16;
      const int row = lin >> 7;
      const int blog = (lin & 127) ^ ((row & 7) << 4);
      const char* sa = (const char*)A + ((size_t)(m0 + row) * DM + k0) * 2 + blog;
      const char* sb = (const char*)Bt + ((size_t)(n0 + row) * DM + k0) * 2 + blog;
      __builtin_amdgcn_global_load_lds((const __attribute__((address_space(1))) void*)sa,
                                       (__attribute__((address_space(3))) void*)((char*)As + lin),
                                       16, 0, 0);
      __builtin_amdgcn_global_load_lds((const __attribute__((address_space(1))) void*)sb,
                                       (__attribute__((address_space(3))) void*)((char*)Bs + lin),
                                       16, 0, 0);
    }
    __syncthreads();
    bf16x8 af[2][4], bfr[2][4];
#pragma unroll
    for (int f = 0; f < 4; ++f) {
      const int ra = wr * 64 + f * 16 + l15;
      const int rb = wc * 64 + f * 16 + l15;
#pragma unroll
      for (int kk = 0; kk < 2; ++kk) {
        const int off = kk * 64 + kg * 16;
        af[kk][f]  = *(const bf16x8*)((const char*)As + ra * 128 + (off ^ ((ra & 7) << 4)));
        bfr[kk][f] = *(const bf16x8*)((const char*)Bs + rb * 128 + (off ^ ((rb & 7) << 4)));
      }
    }
#pragma unroll
    for (int kk = 0; kk < 2; ++kk)
#pragma unroll
      for (int mf = 0; mf < 4; ++mf)
#pragma unroll
        for (int nf = 0; nf < 4; ++nf)
          acc[mf][nf] = __builtin_amdgcn_mfma_f32_16x16x32_bf16(af[kk][mf], bfr[kk][nf],
                                                                acc[mf][nf], 0, 0, 0);
    __syncthreads();
  }
  const int l4 = lane >> 4;
#pragma unroll
  for (int mf = 0; mf < 4; ++mf) {
#pragma unroll
    for (int nf = 0; nf < 4; ++nf) {
#pragma unroll
      for (int r = 0; r < 4; ++r) {
        const int gm = m0 + wr * 64 + mf * 16 + l4 * 4 + r;
        const int gn = n0 + wc * 64 + nf * 16 + l15;
        if (MODE == 0) {
          const float v = 0.05f * bf2f(H0[(size_t)gm * DM + gn]) + 0.95f * acc[mf][nf][r];
          ((unsigned short*)Cout)[(size_t)gm * DM + gn] = f2bf(v);
        } else {
          if (gm < 64)
            ((float*)Cout)[(size_t)blockIdx.y * 64 * DM + (size_t)gm * DM + gn] = acc[mf][nf][r];
        }
      }
    }
  }
}

// ---------------------------------------------------------------------------
// MLP via MFMA: S[o][(b,n)] = sum_c wm[o][c]*ho[b][c][n]; out1 = we·gelu(S+bm)+be
// Block = (1 batch, 64 n). Hop tile staged TRANSPOSED into LDS [n][264-pad].
// ---------------------------------------------------------------------------
__global__ __launch_bounds__(256) void mlp_kernel(const unsigned short* __restrict__ h0,
                                                  const unsigned short* __restrict__ h1,
                                                  const unsigned short* __restrict__ h2,
                                                  const unsigned short* __restrict__ h3,
                                                  const float* __restrict__ wm,
                                                  const float* __restrict__ bm,
                                                  const float* __restrict__ we,
                                                  const float* __restrict__ be,
                                                  unsigned short* __restrict__ out1) {
  __shared__ alignas(16) unsigned short hs[64 * 264];  // [n][c], 528B row stride
  __shared__ alignas(16) unsigned short wl[64 * 264];  // [o][c]
  __shared__ float cbuf[128];                          // bm | we
  const int b = blockIdx.y;
  const int gn0 = blockIdx.x * 64;
  const int tid = threadIdx.x;
  // stage weights (bf16) + bias vectors
  for (int idx = tid; idx < 16384; idx += 256) {
    const int o = idx >> 8, c = idx & 255;
    wl[o * 264 + c] = f2bf(wm[o * 256 + c]);
  }
  if (tid < 64) cbuf[tid] = bm[tid];
  else if (tid < 128) cbuf[tid] = we[tid - 64];
  // stage hop tile transposed: thread reads 8 n for one c, scatter-writes with
  // rotated order so the 8 ds_write_b16 hit distinct bank groups.
  char* hsb = (char*)hs;
#pragma unroll
  for (int it = 0; it < 8; ++it) {
    const int idx = it * 256 + tid;
    const int cf = idx >> 3, n0 = (idx & 7) * 8;
    const int hop = cf >> 6, c = cf & 63;
    const unsigned short* hb = (hop == 0) ? h0 : (hop == 1) ? h1 : (hop == 2) ? h2 : h3;
    const unsigned long long* p =
        (const unsigned long long*)(hb + (size_t)(b * 64 + c) * DM + gn0 + n0);
    const unsigned long long lo = p[0], hi = p[1];
#pragma unroll
    for (int t = 0; t < 8; ++t) {
      const int i = (t + tid) & 7;
      const unsigned short val = (unsigned short)(((i & 4) ? hi : lo) >> ((i & 3) * 16));
      *(unsigned short*)(hsb + (n0 + i) * 528 + cf * 2) = val;
    }
  }
  __syncthreads();
  const int wid = tid >> 6, lane = tid & 63;
  const int l15 = lane & 15, kg = lane >> 4;
  const char* wb = (const char*)wl;
  f32x4 acc[4] = {};
#pragma unroll
  for (int kk = 0; kk < 8; ++kk) {
    const int koff = kk * 64 + kg * 16;
    const bf16x8 bfr = *(const bf16x8*)(hsb + (wid * 16 + l15) * 528 + koff);
#pragma unroll
    for (int mf = 0; mf < 4; ++mf) {
      const bf16x8 af = *(const bf16x8*)(wb + (mf * 16 + l15) * 528 + koff);
      acc[mf] = __builtin_amdgcn_mfma_f32_16x16x32_bf16(af, bfr, acc[mf], 0, 0, 0);
    }
  }
  float pl = 0.f;
#pragma unroll
  for (int mf = 0; mf < 4; ++mf) {
#pragma unroll
    for (int r = 0; r < 4; ++r) {
      const int o = mf * 16 + kg * 4 + r;
      const float s = acc[mf][r] + cbuf[o];
      const float g = 0.5f * s * (1.f + erff(s * 0.70710678118f));
      pl += cbuf[64 + o] * g;
    }
  }
  pl += __shfl_xor(pl, 16);
  pl += __shfl_xor(pl, 32);
  if (kg == 0) {
    const int n = gn0 + wid * 16 + l15;
    out1[(size_t)b * DM + n] = (n < NODE_NUM) ? f2bf(pl + be[0]) : (unsigned short)0;
  }
}

// ---------------------------------------------------------------------------
// w_lin (2048 x 2000 f32) -> bf16 [2048][2048], pad cols zeroed
// ---------------------------------------------------------------------------
__global__ __launch_bounds__(256) void wlin_cvt(const float* __restrict__ wlin,
                                                unsigned short* __restrict__ wl) {
  const int idx = blockIdx.x * 256 + threadIdx.x;
  const int d = idx >> 11, w = idx & 2047;
  wl[idx] = (w < NODE_NUM) ? f2bf(wlin[d * NODE_NUM + w]) : (unsigned short)0;
}

// ---------------------------------------------------------------------------
// sum 8 split-K partials, +b_lin, LayerNorm over 2048, f32 out
// ---------------------------------------------------------------------------
__global__ __launch_bounds__(256) void ln_kernel(const float* __restrict__ yp,
                                                 const float* __restrict__ bl,
                                                 const float* __restrict__ g,
                                                 const float* __restrict__ bb,
                                                 float* __restrict__ out) {
  const int b = blockIdx.x, tid = threadIdx.x;
  __shared__ float rs[4], rq[4];
  float v[8];
  float s = 0.f;
#pragma unroll
  for (int i = 0; i < 8; ++i) {
    const int d = i * 256 + tid;
    float acc = bl[d];
#pragma unroll
    for (int sp = 0; sp < 8; ++sp) acc += yp[(size_t)sp * 64 * DM + (size_t)b * DM + d];
    v[i] = acc;
    s += acc;
  }
  for (int o = 32; o; o >>= 1) s += __shfl_xor(s, o);
  const int wid = tid >> 6, lane = tid & 63;
  if (lane == 0) rs[wid] = s;
  __syncthreads();
  s = rs[0] + rs[1] + rs[2] + rs[3];
  const float mu = s * (1.f / 2048.f);
  float q = 0.f;
#pragma unroll
  for (int i = 0; i < 8; ++i) { const float d = v[i] - mu; q += d * d; }
  for (int o = 32; o; o >>= 1) q += __shfl_xor(q, o);
  if (lane == 0) rq[wid] = q;
  __syncthreads();
  q = rq[0] + rq[1] + rq[2] + rq[3];
  const float inv = rsqrtf(q * (1.f / 2048.f) + 1e-5f);
#pragma unroll
  for (int i = 0; i < 8; ++i) {
    const int d = i * 256 + tid;
    out[(size_t)b * DM + d] = (v[i] - mu) * inv * g[d] + bb[d];
  }
}

// ---------------------------------------------------------------------------
extern "C" void kernel_launch(void* const* d_in, const int* in_sizes, int n_in,
                              void* d_out, int out_size, void* d_ws, size_t ws_size,
                              hipStream_t stream) {
  const float* x      = (const float*)d_in[0];
  const float* nv1    = (const float*)d_in[1];
  const float* nv2    = (const float*)d_in[2];
  const float* w_st   = (const float*)d_in[3];
  const float* b_st   = (const float*)d_in[4];
  const float* w_mlp  = (const float*)d_in[5];
  const float* b_mlp  = (const float*)d_in[6];
  const float* w_end  = (const float*)d_in[7];
  const float* b_end  = (const float*)d_in[8];
  const float* w_lin  = (const float*)d_in[9];
  const float* b_lin  = (const float*)d_in[10];
  const float* ln_g   = (const float*)d_in[11];
  const float* ln_b   = (const float*)d_in[12];

  char* ws = (char*)d_ws;
  const size_t SZ_A = (size_t)DM * DM * 2;    // 8 MB
  const size_t SZ_H = (size_t)4096 * DM * 2;  // 16 MB
  unsigned short* Ab   = (unsigned short*)(ws);
  unsigned short* H0   = (unsigned short*)(ws + SZ_A);
  unsigned short* H1   = (unsigned short*)(ws + SZ_A + SZ_H);
  unsigned short* H2   = (unsigned short*)(ws + SZ_A + 2 * SZ_H);
  unsigned short* H3   = (unsigned short*)(ws + SZ_A + 3 * SZ_H);
  unsigned short* OUT1 = (unsigned short*)(ws + SZ_A + 4 * SZ_H);            // [128][2048]
  unsigned short* WL   = (unsigned short*)(ws + SZ_A + 4 * SZ_H + 524288);   // 8 MB
  float*          YP   = (float*)(ws + SZ_A + 4 * SZ_H + 524288 + SZ_A);     // 8x[64][2048] f32

  adj_kernel<<<256, 256, 0, stream>>>(nv1, nv2, Ab);
  conv_kernel<<<dim3(32, BATCH), 256, 0, stream>>>(x, w_st, b_st, H0);
  wlin_cvt<<<16384, 256, 0, stream>>>(w_lin, WL);

  gemm_nt<0><<<dim3(16, 32), 256, 0, stream>>>(H0, Ab, H0, (void*)H1);
  gemm_nt<0><<<dim3(16, 32), 256, 0, stream>>>(H1, Ab, H0, (void*)H2);
  gemm_nt<0><<<dim3(16, 32), 256, 0, stream>>>(H2, Ab, H0, (void*)H3);

  mlp_kernel<<<dim3(32, BATCH), 256, 0, stream>>>(H0, H1, H2, H3, w_mlp, b_mlp,
                                                  w_end, b_end, OUT1);
  gemm_nt<1><<<dim3(16, 8), 256, 0, stream>>>(OUT1, WL, (const unsigned short*)0, (void*)YP);
  ln_kernel<<<BATCH, 256, 0, stream>>>(YP, b_lin, ln_g, ln_b, (float*)d_out);
}

// Round 6
// 338.351 us; speedup vs baseline: 1.5825x; 1.1187x over previous
//
#include <hip/hip_runtime.h>

#define NODE_NUM 2000
#define DM 2048          // D_MODEL, also padded K/N
#define IN_DIM 7
#define CONV_CH 64
#define KER 49
#define BATCH 64

typedef __attribute__((ext_vector_type(8))) short bf16x8;
typedef __attribute__((ext_vector_type(4))) float f32x4;
typedef __attribute__((ext_vector_type(4))) unsigned int u32x4;

__device__ __forceinline__ float bf2f(unsigned short u) {
  union { unsigned int i; float f; } c; c.i = ((unsigned int)u) << 16; return c.f;
}
__device__ __forceinline__ unsigned short f2bf(float f) {
  union { float f; unsigned int i; } c; c.f = f;
  unsigned int r = c.i + 0x7FFFu + ((c.i >> 16) & 1u);
  return (unsigned short)(r >> 16);
}

// ---------------------------------------------------------------------------
// Adjacency: a[v][w] = (softmax_w(relu(nv1[v]·nv2[:,w])) + (v==w)) / 2
// 8 rows per block, acc[8][8] register tile: 64 FMA per 8 global loads.
// ---------------------------------------------------------------------------
__global__ __launch_bounds__(256) void adj_kernel(const float* __restrict__ nv1,
                                                  const float* __restrict__ nv2,
                                                  unsigned short* __restrict__ Ab) {
  const int bid = blockIdx.x;
  const int tid = threadIdx.x;
  if (bid >= 250) {  // zero pad rows 2000..2047
    const int r0 = 2000 + (bid - 250) * 8;
    for (int i = tid; i < 8 * 2048; i += 256)
      Ab[(size_t)(r0 + (i >> 11)) * DM + (i & 2047)] = 0;
    return;
  }
  const int v0 = bid * 8;
  __shared__ float e1s[8][40];
  __shared__ float redm[8][4], redsum[8][4];
  for (int i = tid; i < 320; i += 256) e1s[i / 40][i % 40] = nv1[(v0 + i / 40) * 40 + i % 40];
  __syncthreads();
  float acc[8][8] = {};
  for (int k = 0; k < 40; ++k) {
    float xv[8];
#pragma unroll
    for (int i = 0; i < 8; ++i) {
      const int w = i * 256 + tid;
      xv[i] = (w < NODE_NUM) ? nv2[k * NODE_NUM + w] : 0.f;
    }
#pragma unroll
    for (int v = 0; v < 8; ++v) {
      const float e = e1s[v][k];
#pragma unroll
      for (int i = 0; i < 8; ++i) acc[v][i] = fmaf(e, xv[i], acc[v][i]);
    }
  }
  const int wid = tid >> 6, lane = tid & 63;
#pragma unroll
  for (int v = 0; v < 8; ++v) {
    float mx = 0.f;
#pragma unroll
    for (int i = 0; i < 8; ++i) {
      const int w = i * 256 + tid;
      const float s = (w < NODE_NUM) ? fmaxf(acc[v][i], 0.f) : -1e30f;
      acc[v][i] = s; mx = fmaxf(mx, s);
    }
    for (int o = 32; o; o >>= 1) mx = fmaxf(mx, __shfl_xor(mx, o));
    if (lane == 0) redm[v][wid] = mx;
  }
  __syncthreads();
#pragma unroll
  for (int v = 0; v < 8; ++v) {
    const float mx = fmaxf(fmaxf(redm[v][0], redm[v][1]), fmaxf(redm[v][2], redm[v][3]));
    float sum = 0.f;
#pragma unroll
    for (int i = 0; i < 8; ++i) { const float e = __expf(acc[v][i] - mx); acc[v][i] = e; sum += e; }
    for (int o = 32; o; o >>= 1) sum += __shfl_xor(sum, o);
    if (lane == 0) redsum[v][wid] = sum;
  }
  __syncthreads();
#pragma unroll
  for (int v = 0; v < 8; ++v) {
    const float sum = redsum[v][0] + redsum[v][1] + redsum[v][2] + redsum[v][3];
    const float inv = 0.5f / sum;
    const int vg = v0 + v;
#pragma unroll
    for (int i = 0; i < 8; ++i) {
      const int w = i * 256 + tid;
      const float val = acc[v][i] * inv + ((w == vg) ? 0.5f : 0.f);
      Ab[(size_t)vg * DM + w] = f2bf(val);
    }
  }
}

// ---------------------------------------------------------------------------
// Pack conv weights into per-lane MFMA A-fragment order (bf16).
// wpack[((kstep*4 + w)*64 + lane)*8 + j] = w[c= w*16+(lane&15)][k = kstep*32+(lane>>4)*8+j]
// where k = ci*64 + kern (kern >= 49 -> 0). 28672 elements.
// ---------------------------------------------------------------------------
__global__ __launch_bounds__(256) void wpack_kernel(const float* __restrict__ wst,
                                                    unsigned short* __restrict__ wpack) {
  const int idx = blockIdx.x * 256 + threadIdx.x;   // 112 blocks
  const int e = idx & 7;
  const int lane = (idx >> 3) & 63;
  const int w = (idx >> 9) & 3;
  const int kstep = idx >> 11;
  const int c = w * 16 + (lane & 15);
  const int k = kstep * 32 + (lane >> 4) * 8 + e;
  const int ci = k >> 6, kern = k & 63;
  const float val = (kern < KER) ? wst[(c * IN_DIM + ci) * KER + kern] : 0.f;
  wpack[idx] = f2bf(val);
}

// ---------------------------------------------------------------------------
// Start conv via MFMA im2col. Block = (n-tile of 64, batch). K padded to 448.
// Bs[kstep][n][kl] bf16 with 16B-slot XOR swizzle; weights A-frags in VGPRs.
// Wave w: channels [w*16, w*16+16) x 64 n. 56 MFMA 16x16x32 per wave.
// ---------------------------------------------------------------------------
__global__ __launch_bounds__(256) void conv_kernel(const float* __restrict__ x,
                                                   const unsigned short* __restrict__ wpack,
                                                   const float* __restrict__ bst,
                                                   unsigned short* __restrict__ H0) {
  __shared__ float xs[IN_DIM][120];                      // x[n0 .. n0+111]
  __shared__ alignas(16) unsigned short Bs[14 * 64 * 32];  // 57344 B
  const int b = blockIdx.y;
  const int n0 = blockIdx.x * 64;
  const int tid = threadIdx.x;
  const int wv = tid >> 6, lane = tid & 63;
  const int l15 = lane & 15, kg = lane >> 4;
  // A-fragments: 14 coalesced 16B loads per lane (weights stay in VGPRs)
  bf16x8 af[14];
#pragma unroll
  for (int ks = 0; ks < 14; ++ks)
    af[ks] = *(const bf16x8*)(wpack + ((size_t)(ks * 4 + wv) * 64 + lane) * 8);
  // bias -> acc init: C row = kg*4 + r  =>  c = wv*16 + kg*4 + r
  f32x4 acc[4];
  {
    const f32x4 bv = *(const f32x4*)(bst + wv * 16 + kg * 4);
#pragma unroll
    for (int nf = 0; nf < 4; ++nf) acc[nf] = bv;
  }
  // stage x tile (f32, coalesced)
  for (int i = tid; i < IN_DIM * 112; i += 256) {
    const int ci = i / 112, p = i % 112;
    const int gx = n0 + p;
    xs[ci][p] = (gx < DM) ? x[(size_t)b * (IN_DIM * DM) + ci * DM + gx] : 0.f;
  }
  __syncthreads();
  // build im2col Bs: chunk = (kstep, n, kg2) -> 8 consecutive k
  for (int it = 0; it < 14; ++it) {
    const int idx = it * 256 + tid;
    const int kg2 = idx & 3, n = (idx >> 2) & 63, ks = idx >> 8;
    const int k0 = ks * 32 + kg2 * 8;
    const int ci = k0 >> 6, kern0 = k0 & 63;
    bf16x8 v;
#pragma unroll
    for (int j = 0; j < 8; ++j) {
      const int kern = kern0 + j;
      v[j] = (short)((kern < KER) ? f2bf(xs[ci][n + kern]) : (unsigned short)0);
    }
    const int byte = ks * 4096 + ((n * 64 + kg2 * 16) ^ (((n >> 1) & 3) << 4));
    *(bf16x8*)((char*)Bs + byte) = v;
  }
  __syncthreads();
  // MFMA main loop
#pragma unroll
  for (int ks = 0; ks < 14; ++ks) {
#pragma unroll
    for (int nf = 0; nf < 4; ++nf) {
      const int n = nf * 16 + l15;
      const int byte = ks * 4096 + ((n * 64 + kg * 16) ^ (((n >> 1) & 3) << 4));
      const bf16x8 bfr = *(const bf16x8*)((const char*)Bs + byte);
      acc[nf] = __builtin_amdgcn_mfma_f32_16x16x32_bf16(af[ks], bfr, acc[nf], 0, 0, 0);
    }
  }
  // epilogue: c = wv*16 + kg*4 + r, n = n0 + nf*16 + l15
#pragma unroll
  for (int nf = 0; nf < 4; ++nf) {
#pragma unroll
    for (int r = 0; r < 4; ++r) {
      const int c = wv * 16 + kg * 4 + r;
      const int n = n0 + nf * 16 + l15;
      H0[(size_t)(b * 64 + c) * DM + n] =
          (n < NODE_NUM) ? f2bf(acc[nf][r]) : (unsigned short)0;
    }
  }
}

// ---------------------------------------------------------------------------
// NT-GEMM: C[m][n] = sum_k A[m][k] * Bt[n][k], lda=ldb=ldc=2048.
// MODE 0: full K, mixprop epilogue  out = bf16(0.05*H0 + 0.95*acc)
// MODE 1: split-K (blockIdx.y = split of 256 k's), m0=0, f32 partial out
// ---------------------------------------------------------------------------
template <int MODE>
__global__ __launch_bounds__(256) void gemm_nt(const unsigned short* __restrict__ A,
                                               const unsigned short* __restrict__ Bt,
                                               const unsigned short* __restrict__ H0,
                                               void* __restrict__ Cout) {
  __shared__ alignas(16) unsigned short As[128 * 64];
  __shared__ alignas(16) unsigned short Bs[128 * 64];
  const int tid = threadIdx.x;
  const int n0 = blockIdx.x * 128;
  const int m0 = (MODE == 0) ? blockIdx.y * 128 : 0;
  const int kbeg = (MODE == 0) ? 0 : blockIdx.y * 256;
  const int kend = (MODE == 0) ? DM : kbeg + 256;
  const int wid = tid >> 6, lane = tid & 63;
  const int wr = wid >> 1, wc = wid & 1;
  const int l15 = lane & 15, kg = lane >> 4;
  f32x4 acc[4][4] = {};
  for (int k0 = kbeg; k0 < kend; k0 += 64) {
#pragma unroll
    for (int it = 0; it < 4; ++it) {
      const int lin = it * 4096 + tid * 16;
      const int row = lin >> 7;
      const int blog = (lin & 127) ^ ((row & 7) << 4);
      const char* sa = (const char*)A + ((size_t)(m0 + row) * DM + k0) * 2 + blog;
      const char* sb = (const char*)Bt + ((size_t)(n0 + row) * DM + k0) * 2 + blog;
      __builtin_amdgcn_global_load_lds((const __attribute__((address_space(1))) void*)sa,
                                       (__attribute__((address_space(3))) void*)((char*)As + lin),
                                       16, 0, 0);
      __builtin_amdgcn_global_load_lds((const __attribute__((address_space(1))) void*)sb,
                                       (__attribute__((address_space(3))) void*)((char*)Bs + lin),
                                       16, 0, 0);
    }
    __syncthreads();
    bf16x8 af[2][4], bfr[2][4];
#pragma unroll
    for (int f = 0; f < 4; ++f) {
      const int ra = wr * 64 + f * 16 + l15;
      const int rb = wc * 64 + f * 16 + l15;
#pragma unroll
      for (int kk = 0; kk < 2; ++kk) {
        const int off = kk * 64 + kg * 16;
        af[kk][f]  = *(const bf16x8*)((const char*)As + ra * 128 + (off ^ ((ra & 7) << 4)));
        bfr[kk][f] = *(const bf16x8*)((const char*)Bs + rb * 128 + (off ^ ((rb & 7) << 4)));
      }
    }
#pragma unroll
    for (int kk = 0; kk < 2; ++kk)
#pragma unroll
      for (int mf = 0; mf < 4; ++mf)
#pragma unroll
        for (int nf = 0; nf < 4; ++nf)
          acc[mf][nf] = __builtin_amdgcn_mfma_f32_16x16x32_bf16(af[kk][mf], bfr[kk][nf],
                                                                acc[mf][nf], 0, 0, 0);
    __syncthreads();
  }
  const int l4 = lane >> 4;
#pragma unroll
  for (int mf = 0; mf < 4; ++mf) {
#pragma unroll
    for (int nf = 0; nf < 4; ++nf) {
#pragma unroll
      for (int r = 0; r < 4; ++r) {
        const int gm = m0 + wr * 64 + mf * 16 + l4 * 4 + r;
        const int gn = n0 + wc * 64 + nf * 16 + l15;
        if (MODE == 0) {
          const float v = 0.05f * bf2f(H0[(size_t)gm * DM + gn]) + 0.95f * acc[mf][nf][r];
          ((unsigned short*)Cout)[(size_t)gm * DM + gn] = f2bf(v);
        } else {
          if (gm < 64)
            ((float*)Cout)[(size_t)blockIdx.y * 64 * DM + (size_t)gm * DM + gn] = acc[mf][nf][r];
        }
      }
    }
  }
}

// ---------------------------------------------------------------------------
// MLP via MFMA: S[o][(b,n)] = sum_c wm[o][c]*ho[b][c][n]; out1 = we·gelu(S+bm)+be
// Block = (1 batch, 64 n). Hop tile staged TRANSPOSED into LDS [n][264-pad].
// ---------------------------------------------------------------------------
__global__ __launch_bounds__(256) void mlp_kernel(const unsigned short* __restrict__ h0,
                                                  const unsigned short* __restrict__ h1,
                                                  const unsigned short* __restrict__ h2,
                                                  const unsigned short* __restrict__ h3,
                                                  const float* __restrict__ wm,
                                                  const float* __restrict__ bm,
                                                  const float* __restrict__ we,
                                                  const float* __restrict__ be,
                                                  unsigned short* __restrict__ out1) {
  __shared__ alignas(16) unsigned short hs[64 * 264];  // [n][c], 528B row stride
  __shared__ alignas(16) unsigned short wl[64 * 264];  // [o][c]
  __shared__ float cbuf[128];                          // bm | we
  const int b = blockIdx.y;
  const int gn0 = blockIdx.x * 64;
  const int tid = threadIdx.x;
  // stage weights (bf16) + bias vectors
  for (int idx = tid; idx < 16384; idx += 256) {
    const int o = idx >> 8, c = idx & 255;
    wl[o * 264 + c] = f2bf(wm[o * 256 + c]);
  }
  if (tid < 64) cbuf[tid] = bm[tid];
  else if (tid < 128) cbuf[tid] = we[tid - 64];
  // stage hop tile transposed: thread reads 8 n for one c, scatter-writes with
  // rotated order so the 8 ds_write_b16 hit distinct bank groups.
  char* hsb = (char*)hs;
#pragma unroll
  for (int it = 0; it < 8; ++it) {
    const int idx = it * 256 + tid;
    const int cf = idx >> 3, n0 = (idx & 7) * 8;
    const int hop = cf >> 6, c = cf & 63;
    const unsigned short* hb = (hop == 0) ? h0 : (hop == 1) ? h1 : (hop == 2) ? h2 : h3;
    const unsigned long long* p =
        (const unsigned long long*)(hb + (size_t)(b * 64 + c) * DM + gn0 + n0);
    const unsigned long long lo = p[0], hi = p[1];
#pragma unroll
    for (int t = 0; t < 8; ++t) {
      const int i = (t + tid) & 7;
      const unsigned short val = (unsigned short)(((i & 4) ? hi : lo) >> ((i & 3) * 16));
      *(unsigned short*)(hsb + (n0 + i) * 528 + cf * 2) = val;
    }
  }
  __syncthreads();
  const int wid = tid >> 6, lane = tid & 63;
  const int l15 = lane & 15, kg = lane >> 4;
  const char* wb = (const char*)wl;
  f32x4 acc[4] = {};
#pragma unroll
  for (int kk = 0; kk < 8; ++kk) {
    const int koff = kk * 64 + kg * 16;
    const bf16x8 bfr = *(const bf16x8*)(hsb + (wid * 16 + l15) * 528 + koff);
#pragma unroll
    for (int mf = 0; mf < 4; ++mf) {
      const bf16x8 af = *(const bf16x8*)(wb + (mf * 16 + l15) * 528 + koff);
      acc[mf] = __builtin_amdgcn_mfma_f32_16x16x32_bf16(af, bfr, acc[mf], 0, 0, 0);
    }
  }
  float pl = 0.f;
#pragma unroll
  for (int mf = 0; mf < 4; ++mf) {
#pragma unroll
    for (int r = 0; r < 4; ++r) {
      const int o = mf * 16 + kg * 4 + r;
      const float s = acc[mf][r] + cbuf[o];
      const float g = 0.5f * s * (1.f + erff(s * 0.70710678118f));
      pl += cbuf[64 + o] * g;
    }
  }
  pl += __shfl_xor(pl, 16);
  pl += __shfl_xor(pl, 32);
  if (kg == 0) {
    const int n = gn0 + wid * 16 + l15;
    out1[(size_t)b * DM + n] = (n < NODE_NUM) ? f2bf(pl + be[0]) : (unsigned short)0;
  }
}

// ---------------------------------------------------------------------------
// w_lin (2048 x 2000 f32) -> bf16 [2048][2048], pad cols zeroed
// ---------------------------------------------------------------------------
__global__ __launch_bounds__(256) void wlin_cvt(const float* __restrict__ wlin,
                                                unsigned short* __restrict__ wl) {
  const int idx = blockIdx.x * 256 + threadIdx.x;
  const int d = idx >> 11, w = idx & 2047;
  wl[idx] = (w < NODE_NUM) ? f2bf(wlin[d * NODE_NUM + w]) : (unsigned short)0;
}

// ---------------------------------------------------------------------------
// sum 8 split-K partials, +b_lin, LayerNorm over 2048, f32 out
// ---------------------------------------------------------------------------
__global__ __launch_bounds__(256) void ln_kernel(const float* __restrict__ yp,
                                                 const float* __restrict__ bl,
                                                 const float* __restrict__ g,
                                                 const float* __restrict__ bb,
                                                 float* __restrict__ out) {
  const int b = blockIdx.x, tid = threadIdx.x;
  __shared__ float rs[4], rq[4];
  float v[8];
  float s = 0.f;
#pragma unroll
  for (int i = 0; i < 8; ++i) {
    const int d = i * 256 + tid;
    float acc = bl[d];
#pragma unroll
    for (int sp = 0; sp < 8; ++sp) acc += yp[(size_t)sp * 64 * DM + (size_t)b * DM + d];
    v[i] = acc;
    s += acc;
  }
  for (int o = 32; o; o >>= 1) s += __shfl_xor(s, o);
  const int wid = tid >> 6, lane = tid & 63;
  if (lane == 0) rs[wid] = s;
  __syncthreads();
  s = rs[0] + rs[1] + rs[2] + rs[3];
  const float mu = s * (1.f / 2048.f);
  float q = 0.f;
#pragma unroll
  for (int i = 0; i < 8; ++i) { const float d = v[i] - mu; q += d * d; }
  for (int o = 32; o; o >>= 1) q += __shfl_xor(q, o);
  if (lane == 0) rq[wid] = q;
  __syncthreads();
  q = rq[0] + rq[1] + rq[2] + rq[3];
  const float inv = rsqrtf(q * (1.f / 2048.f) + 1e-5f);
#pragma unroll
  for (int i = 0; i < 8; ++i) {
    const int d = i * 256 + tid;
    out[(size_t)b * DM + d] = (v[i] - mu) * inv * g[d] + bb[d];
  }
}

// ---------------------------------------------------------------------------
extern "C" void kernel_launch(void* const* d_in, const int* in_sizes, int n_in,
                              void* d_out, int out_size, void* d_ws, size_t ws_size,
                              hipStream_t stream) {
  const float* x      = (const float*)d_in[0];
  const float* nv1    = (const float*)d_in[1];
  const float* nv2    = (const float*)d_in[2];
  const float* w_st   = (const float*)d_in[3];
  const float* b_st   = (const float*)d_in[4];
  const float* w_mlp  = (const float*)d_in[5];
  const float* b_mlp  = (const float*)d_in[6];
  const float* w_end  = (const float*)d_in[7];
  const float* b_end  = (const float*)d_in[8];
  const float* w_lin  = (const float*)d_in[9];
  const float* b_lin  = (const float*)d_in[10];
  const float* ln_g   = (const float*)d_in[11];
  const float* ln_b   = (const float*)d_in[12];

  char* ws = (char*)d_ws;
  const size_t SZ_A = (size_t)DM * DM * 2;    // 8 MB
  const size_t SZ_H = (size_t)4096 * DM * 2;  // 16 MB
  unsigned short* Ab    = (unsigned short*)(ws);
  unsigned short* H0    = (unsigned short*)(ws + SZ_A);
  unsigned short* H1    = (unsigned short*)(ws + SZ_A + SZ_H);
  unsigned short* H2    = (unsigned short*)(ws + SZ_A + 2 * SZ_H);
  unsigned short* H3    = (unsigned short*)(ws + SZ_A + 3 * SZ_H);
  unsigned short* OUT1  = (unsigned short*)(ws + SZ_A + 4 * SZ_H);           // [64][2048] used
  unsigned short* WPACK = (unsigned short*)(ws + SZ_A + 4 * SZ_H + 262144);  // 57344 B
  unsigned short* WL    = (unsigned short*)(ws + SZ_A + 4 * SZ_H + 524288);  // 8 MB
  float*          YP    = (float*)(ws + SZ_A + 4 * SZ_H + 524288 + SZ_A);    // 8x[64][2048] f32

  wpack_kernel<<<112, 256, 0, stream>>>(w_st, WPACK);
  adj_kernel<<<256, 256, 0, stream>>>(nv1, nv2, Ab);
  conv_kernel<<<dim3(32, BATCH), 256, 0, stream>>>(x, WPACK, b_st, H0);
  wlin_cvt<<<16384, 256, 0, stream>>>(w_lin, WL);

  gemm_nt<0><<<dim3(16, 32), 256, 0, stream>>>(H0, Ab, H0, (void*)H1);
  gemm_nt<0><<<dim3(16, 32), 256, 0, stream>>>(H1, Ab, H0, (void*)H2);
  gemm_nt<0><<<dim3(16, 32), 256, 0, stream>>>(H2, Ab, H0, (void*)H3);

  mlp_kernel<<<dim3(32, BATCH), 256, 0, stream>>>(H0, H1, H2, H3, w_mlp, b_mlp,
                                                  w_end, b_end, OUT1);
  gemm_nt<1><<<dim3(16, 8), 256, 0, stream>>>(OUT1, WL, (const unsigned short*)0, (void*)YP);
  ln_kernel<<<BATCH, 256, 0, stream>>>(YP, b_lin, ln_g, ln_b, (float*)d_out);
}

// Round 7
// 320.242 us; speedup vs baseline: 1.6719x; 1.0565x over previous
//
#include <hip/hip_runtime.h>

#define NODE_NUM 2000
#define DM 2048          // D_MODEL, also padded K/N
#define IN_DIM 7
#define CONV_CH 64
#define KER 49
#define BATCH 64

typedef __attribute__((ext_vector_type(8))) short bf16x8;
typedef __attribute__((ext_vector_type(4))) float f32x4;
typedef __attribute__((ext_vector_type(4))) unsigned int u32x4;

__device__ __forceinline__ float bf2f(unsigned short u) {
  union { unsigned int i; float f; } c; c.i = ((unsigned int)u) << 16; return c.f;
}
__device__ __forceinline__ unsigned short f2bf(float f) {
  union { float f; unsigned int i; } c; c.f = f;
  unsigned int r = c.i + 0x7FFFu + ((c.i >> 16) & 1u);
  return (unsigned short)(r >> 16);
}

// ---------------------------------------------------------------------------
// Adjacency: a[v][w] = (softmax_w(relu(nv1[v]·nv2[:,w])) + (v==w)) / 2
// ---------------------------------------------------------------------------
__global__ __launch_bounds__(256) void adj_kernel(const float* __restrict__ nv1,
                                                  const float* __restrict__ nv2,
                                                  unsigned short* __restrict__ Ab) {
  const int bid = blockIdx.x;
  const int tid = threadIdx.x;
  if (bid >= 250) {  // zero pad rows 2000..2047
    const int r0 = 2000 + (bid - 250) * 8;
    for (int i = tid; i < 8 * 2048; i += 256)
      Ab[(size_t)(r0 + (i >> 11)) * DM + (i & 2047)] = 0;
    return;
  }
  const int v0 = bid * 8;
  __shared__ float e1s[8][40];
  __shared__ float redm[8][4], redsum[8][4];
  for (int i = tid; i < 320; i += 256) e1s[i / 40][i % 40] = nv1[(v0 + i / 40) * 40 + i % 40];
  __syncthreads();
  float acc[8][8] = {};
  for (int k = 0; k < 40; ++k) {
    float xv[8];
#pragma unroll
    for (int i = 0; i < 8; ++i) {
      const int w = i * 256 + tid;
      xv[i] = (w < NODE_NUM) ? nv2[k * NODE_NUM + w] : 0.f;
    }
#pragma unroll
    for (int v = 0; v < 8; ++v) {
      const float e = e1s[v][k];
#pragma unroll
      for (int i = 0; i < 8; ++i) acc[v][i] = fmaf(e, xv[i], acc[v][i]);
    }
  }
  const int wid = tid >> 6, lane = tid & 63;
#pragma unroll
  for (int v = 0; v < 8; ++v) {
    float mx = 0.f;
#pragma unroll
    for (int i = 0; i < 8; ++i) {
      const int w = i * 256 + tid;
      const float s = (w < NODE_NUM) ? fmaxf(acc[v][i], 0.f) : -1e30f;
      acc[v][i] = s; mx = fmaxf(mx, s);
    }
    for (int o = 32; o; o >>= 1) mx = fmaxf(mx, __shfl_xor(mx, o));
    if (lane == 0) redm[v][wid] = mx;
  }
  __syncthreads();
#pragma unroll
  for (int v = 0; v < 8; ++v) {
    const float mx = fmaxf(fmaxf(redm[v][0], redm[v][1]), fmaxf(redm[v][2], redm[v][3]));
    float sum = 0.f;
#pragma unroll
    for (int i = 0; i < 8; ++i) { const float e = __expf(acc[v][i] - mx); acc[v][i] = e; sum += e; }
    for (int o = 32; o; o >>= 1) sum += __shfl_xor(sum, o);
    if (lane == 0) redsum[v][wid] = sum;
  }
  __syncthreads();
#pragma unroll
  for (int v = 0; v < 8; ++v) {
    const float sum = redsum[v][0] + redsum[v][1] + redsum[v][2] + redsum[v][3];
    const float inv = 0.5f / sum;
    const int vg = v0 + v;
#pragma unroll
    for (int i = 0; i < 8; ++i) {
      const int w = i * 256 + tid;
      const float val = acc[v][i] * inv + ((w == vg) ? 0.5f : 0.f);
      Ab[(size_t)vg * DM + w] = f2bf(val);
    }
  }
}

// ---------------------------------------------------------------------------
// Pack conv weights into per-lane MFMA A-fragment order (bf16).
// ---------------------------------------------------------------------------
__global__ __launch_bounds__(256) void wpack_kernel(const float* __restrict__ wst,
                                                    unsigned short* __restrict__ wpack) {
  const int idx = blockIdx.x * 256 + threadIdx.x;   // 112 blocks
  const int e = idx & 7;
  const int lane = (idx >> 3) & 63;
  const int w = (idx >> 9) & 3;
  const int kstep = idx >> 11;
  const int c = w * 16 + (lane & 15);
  const int k = kstep * 32 + (lane >> 4) * 8 + e;
  const int ci = k >> 6, kern = k & 63;
  const float val = (kern < KER) ? wst[(c * IN_DIM + ci) * KER + kern] : 0.f;
  wpack[idx] = f2bf(val);
}

// ---------------------------------------------------------------------------
// Start conv via MFMA im2col (round-4 verified structure).
// ---------------------------------------------------------------------------
__global__ __launch_bounds__(256) void conv_kernel(const float* __restrict__ x,
                                                   const unsigned short* __restrict__ wpack,
                                                   const float* __restrict__ bst,
                                                   unsigned short* __restrict__ H0) {
  __shared__ float xs[IN_DIM][120];
  __shared__ alignas(16) unsigned short Bs[14 * 64 * 32];
  const int b = blockIdx.y;
  const int n0 = blockIdx.x * 64;
  const int tid = threadIdx.x;
  const int wv = tid >> 6, lane = tid & 63;
  const int l15 = lane & 15, kg = lane >> 4;
  bf16x8 af[14];
#pragma unroll
  for (int ks = 0; ks < 14; ++ks)
    af[ks] = *(const bf16x8*)(wpack + ((size_t)(ks * 4 + wv) * 64 + lane) * 8);
  f32x4 acc[4];
  {
    const f32x4 bv = *(const f32x4*)(bst + wv * 16 + kg * 4);
#pragma unroll
    for (int nf = 0; nf < 4; ++nf) acc[nf] = bv;
  }
  for (int i = tid; i < IN_DIM * 112; i += 256) {
    const int ci = i / 112, p = i % 112;
    const int gx = n0 + p;
    xs[ci][p] = (gx < DM) ? x[(size_t)b * (IN_DIM * DM) + ci * DM + gx] : 0.f;
  }
  __syncthreads();
  for (int it = 0; it < 14; ++it) {
    const int idx = it * 256 + tid;
    const int kg2 = idx & 3, n = (idx >> 2) & 63, ks = idx >> 8;
    const int k0 = ks * 32 + kg2 * 8;
    const int ci = k0 >> 6, kern0 = k0 & 63;
    bf16x8 v;
#pragma unroll
    for (int j = 0; j < 8; ++j) {
      const int kern = kern0 + j;
      v[j] = (short)((kern < KER) ? f2bf(xs[ci][n + kern]) : (unsigned short)0);
    }
    const int byte = ks * 4096 + ((n * 64 + kg2 * 16) ^ (((n >> 1) & 3) << 4));
    *(bf16x8*)((char*)Bs + byte) = v;
  }
  __syncthreads();
#pragma unroll
  for (int ks = 0; ks < 14; ++ks) {
#pragma unroll
    for (int nf = 0; nf < 4; ++nf) {
      const int n = nf * 16 + l15;
      const int byte = ks * 4096 + ((n * 64 + kg * 16) ^ (((n >> 1) & 3) << 4));
      const bf16x8 bfr = *(const bf16x8*)((const char*)Bs + byte);
      acc[nf] = __builtin_amdgcn_mfma_f32_16x16x32_bf16(af[ks], bfr, acc[nf], 0, 0, 0);
    }
  }
#pragma unroll
  for (int nf = 0; nf < 4; ++nf) {
#pragma unroll
    for (int r = 0; r < 4; ++r) {
      const int c = wv * 16 + kg * 4 + r;
      const int n = n0 + nf * 16 + l15;
      H0[(size_t)(b * 64 + c) * DM + n] =
          (n < NODE_NUM) ? f2bf(acc[nf][r]) : (unsigned short)0;
    }
  }
}

// ---------------------------------------------------------------------------
// NT-GEMM: C[m][n] = sum_k A[m][k] * Bt[n][k], lda=ldb=ldc=2048.
// Depth-2 counted-vmcnt pipeline (T3/T4): dbuf LDS, STAGE(t+2) in flight,
// vmcnt(8) waits only the older tile's 8 loads; raw barriers (no full drain).
// MODE 0: full K, mixprop epilogue  out = bf16(0.05*H0 + 0.95*acc)
// MODE 1: split-K (blockIdx.y = split of 256 k's), m0=0, f32 partial out
// ---------------------------------------------------------------------------
template <int MODE>
__global__ __launch_bounds__(256) void gemm_nt(const unsigned short* __restrict__ A,
                                               const unsigned short* __restrict__ Bt,
                                               const unsigned short* __restrict__ H0,
                                               void* __restrict__ Cout) {
  __shared__ alignas(16) unsigned short As[2][128 * 64];
  __shared__ alignas(16) unsigned short Bs[2][128 * 64];
  const int tid = threadIdx.x;
  const int n0 = blockIdx.x * 128;
  const int m0 = (MODE == 0) ? blockIdx.y * 128 : 0;
  const int kbeg = (MODE == 0) ? 0 : blockIdx.y * 256;
  const int nt = (MODE == 0) ? (DM / 64) : 4;   // always >= 2
  const int wid = tid >> 6, lane = tid & 63;
  const int wr = wid >> 1, wc = wid & 1;
  const int l15 = lane & 15, kg = lane >> 4;

  auto STAGE = [&](int buf, int k0) {
#pragma unroll
    for (int it = 0; it < 4; ++it) {
      const int lin = it * 4096 + tid * 16;
      const int row = lin >> 7;
      const int blog = (lin & 127) ^ ((row & 7) << 4);   // inverse swizzle -> logical
      const char* sa = (const char*)A + ((size_t)(m0 + row) * DM + k0) * 2 + blog;
      const char* sb = (const char*)Bt + ((size_t)(n0 + row) * DM + k0) * 2 + blog;
      __builtin_amdgcn_global_load_lds((const __attribute__((address_space(1))) void*)sa,
                                       (__attribute__((address_space(3))) void*)((char*)As[buf] + lin),
                                       16, 0, 0);
      __builtin_amdgcn_global_load_lds((const __attribute__((address_space(1))) void*)sb,
                                       (__attribute__((address_space(3))) void*)((char*)Bs[buf] + lin),
                                       16, 0, 0);
    }
  };

  f32x4 acc[4][4] = {};
  STAGE(0, kbeg);
  STAGE(1, kbeg + 64);

  for (int t = 0; t < nt; ++t) {
    const int cur = t & 1;
    // wait for tile t (the 8 oldest of up to 16 outstanding loads)
    if (t + 1 < nt) asm volatile("s_waitcnt vmcnt(8)" ::: "memory");
    else            asm volatile("s_waitcnt vmcnt(0)" ::: "memory");
    __builtin_amdgcn_s_barrier();            // all waves: tile t resident
    __builtin_amdgcn_sched_barrier(0);
    bf16x8 af[2][4], bfr[2][4];
#pragma unroll
    for (int f = 0; f < 4; ++f) {
      const int ra = wr * 64 + f * 16 + l15;
      const int rb = wc * 64 + f * 16 + l15;
#pragma unroll
      for (int kk = 0; kk < 2; ++kk) {
        const int off = kk * 64 + kg * 16;
        af[kk][f]  = *(const bf16x8*)((const char*)As[cur] + ra * 128 + (off ^ ((ra & 7) << 4)));
        bfr[kk][f] = *(const bf16x8*)((const char*)Bs[cur] + rb * 128 + (off ^ ((rb & 7) << 4)));
      }
    }
    asm volatile("s_waitcnt lgkmcnt(0)" ::: "memory");  // this wave's reads landed
    __builtin_amdgcn_sched_barrier(0);
    __builtin_amdgcn_s_barrier();            // all waves done reading buf[cur]
    __builtin_amdgcn_sched_barrier(0);
    if (t + 2 < nt) STAGE(cur, kbeg + (t + 2) * 64);    // overwrite is now safe
#pragma unroll
    for (int kk = 0; kk < 2; ++kk)
#pragma unroll
      for (int mf = 0; mf < 4; ++mf)
#pragma unroll
        for (int nf = 0; nf < 4; ++nf)
          acc[mf][nf] = __builtin_amdgcn_mfma_f32_16x16x32_bf16(af[kk][mf], bfr[kk][nf],
                                                                acc[mf][nf], 0, 0, 0);
  }
  const int l4 = lane >> 4;
#pragma unroll
  for (int mf = 0; mf < 4; ++mf) {
#pragma unroll
    for (int nf = 0; nf < 4; ++nf) {
#pragma unroll
      for (int r = 0; r < 4; ++r) {
        const int gm = m0 + wr * 64 + mf * 16 + l4 * 4 + r;
        const int gn = n0 + wc * 64 + nf * 16 + l15;
        if (MODE == 0) {
          const float v = 0.05f * bf2f(H0[(size_t)gm * DM + gn]) + 0.95f * acc[mf][nf][r];
          ((unsigned short*)Cout)[(size_t)gm * DM + gn] = f2bf(v);
        } else {
          if (gm < 64)
            ((float*)Cout)[(size_t)blockIdx.y * 64 * DM + (size_t)gm * DM + gn] = acc[mf][nf][r];
        }
      }
    }
  }
}

// ---------------------------------------------------------------------------
// MLP via MFMA (round-1 verified structure).
// ---------------------------------------------------------------------------
__global__ __launch_bounds__(256) void mlp_kernel(const unsigned short* __restrict__ h0,
                                                  const unsigned short* __restrict__ h1,
                                                  const unsigned short* __restrict__ h2,
                                                  const unsigned short* __restrict__ h3,
                                                  const float* __restrict__ wm,
                                                  const float* __restrict__ bm,
                                                  const float* __restrict__ we,
                                                  const float* __restrict__ be,
                                                  unsigned short* __restrict__ out1) {
  __shared__ alignas(16) unsigned short hs[64 * 264];  // [n][c], 528B row stride
  __shared__ alignas(16) unsigned short wl[64 * 264];  // [o][c]
  __shared__ float cbuf[128];                          // bm | we
  const int b = blockIdx.y;
  const int gn0 = blockIdx.x * 64;
  const int tid = threadIdx.x;
  for (int idx = tid; idx < 16384; idx += 256) {
    const int o = idx >> 8, c = idx & 255;
    wl[o * 264 + c] = f2bf(wm[o * 256 + c]);
  }
  if (tid < 64) cbuf[tid] = bm[tid];
  else if (tid < 128) cbuf[tid] = we[tid - 64];
  char* hsb = (char*)hs;
#pragma unroll
  for (int it = 0; it < 8; ++it) {
    const int idx = it * 256 + tid;
    const int cf = idx >> 3, n0 = (idx & 7) * 8;
    const int hop = cf >> 6, c = cf & 63;
    const unsigned short* hb = (hop == 0) ? h0 : (hop == 1) ? h1 : (hop == 2) ? h2 : h3;
    const unsigned long long* p =
        (const unsigned long long*)(hb + (size_t)(b * 64 + c) * DM + gn0 + n0);
    const unsigned long long lo = p[0], hi = p[1];
#pragma unroll
    for (int t = 0; t < 8; ++t) {
      const int i = (t + tid) & 7;
      const unsigned short val = (unsigned short)(((i & 4) ? hi : lo) >> ((i & 3) * 16));
      *(unsigned short*)(hsb + (n0 + i) * 528 + cf * 2) = val;
    }
  }
  __syncthreads();
  const int wid = tid >> 6, lane = tid & 63;
  const int l15 = lane & 15, kg = lane >> 4;
  const char* wb = (const char*)wl;
  f32x4 acc[4] = {};
#pragma unroll
  for (int kk = 0; kk < 8; ++kk) {
    const int koff = kk * 64 + kg * 16;
    const bf16x8 bfr = *(const bf16x8*)(hsb + (wid * 16 + l15) * 528 + koff);
#pragma unroll
    for (int mf = 0; mf < 4; ++mf) {
      const bf16x8 af = *(const bf16x8*)(wb + (mf * 16 + l15) * 528 + koff);
      acc[mf] = __builtin_amdgcn_mfma_f32_16x16x32_bf16(af, bfr, acc[mf], 0, 0, 0);
    }
  }
  float pl = 0.f;
#pragma unroll
  for (int mf = 0; mf < 4; ++mf) {
#pragma unroll
    for (int r = 0; r < 4; ++r) {
      const int o = mf * 16 + kg * 4 + r;
      const float s = acc[mf][r] + cbuf[o];
      const float g = 0.5f * s * (1.f + erff(s * 0.70710678118f));
      pl += cbuf[64 + o] * g;
    }
  }
  pl += __shfl_xor(pl, 16);
  pl += __shfl_xor(pl, 32);
  if (kg == 0) {
    const int n = gn0 + wid * 16 + l15;
    out1[(size_t)b * DM + n] = (n < NODE_NUM) ? f2bf(pl + be[0]) : (unsigned short)0;
  }
}

// ---------------------------------------------------------------------------
// w_lin (2048 x 2000 f32) -> bf16 [2048][2048], pad cols zeroed (vectorized)
// ---------------------------------------------------------------------------
__global__ __launch_bounds__(256) void wlin_cvt(const float* __restrict__ wlin,
                                                unsigned short* __restrict__ wl) {
  const int idx = (blockIdx.x * 256 + threadIdx.x) * 8;   // 2048 blocks
  const int d = idx >> 11, w0 = idx & 2047;
  unsigned short out[8];
#pragma unroll
  for (int j = 0; j < 8; ++j) {
    const int w = w0 + j;
    out[j] = (w < NODE_NUM) ? f2bf(wlin[d * NODE_NUM + w]) : (unsigned short)0;
  }
  *(u32x4*)(wl + idx) = *(const u32x4*)out;
}

// ---------------------------------------------------------------------------
// sum 8 split-K partials, +b_lin, LayerNorm over 2048, f32 out
// ---------------------------------------------------------------------------
__global__ __launch_bounds__(256) void ln_kernel(const float* __restrict__ yp,
                                                 const float* __restrict__ bl,
                                                 const float* __restrict__ g,
                                                 const float* __restrict__ bb,
                                                 float* __restrict__ out) {
  const int b = blockIdx.x, tid = threadIdx.x;
  __shared__ float rs[4], rq[4];
  float v[8];
  float s = 0.f;
#pragma unroll
  for (int i = 0; i < 8; ++i) {
    const int d = i * 256 + tid;
    float acc = bl[d];
#pragma unroll
    for (int sp = 0; sp < 8; ++sp) acc += yp[(size_t)sp * 64 * DM + (size_t)b * DM + d];
    v[i] = acc;
    s += acc;
  }
  for (int o = 32; o; o >>= 1) s += __shfl_xor(s, o);
  const int wid = tid >> 6, lane = tid & 63;
  if (lane == 0) rs[wid] = s;
  __syncthreads();
  s = rs[0] + rs[1] + rs[2] + rs[3];
  const float mu = s * (1.f / 2048.f);
  float q = 0.f;
#pragma unroll
  for (int i = 0; i < 8; ++i) { const float d = v[i] - mu; q += d * d; }
  for (int o = 32; o; o >>= 1) q += __shfl_xor(q, o);
  if (lane == 0) rq[wid] = q;
  __syncthreads();
  q = rq[0] + rq[1] + rq[2] + rq[3];
  const float inv = rsqrtf(q * (1.f / 2048.f) + 1e-5f);
#pragma unroll
  for (int i = 0; i < 8; ++i) {
    const int d = i * 256 + tid;
    out[(size_t)b * DM + d] = (v[i] - mu) * inv * g[d] + bb[d];
  }
}

// ---------------------------------------------------------------------------
extern "C" void kernel_launch(void* const* d_in, const int* in_sizes, int n_in,
                              void* d_out, int out_size, void* d_ws, size_t ws_size,
                              hipStream_t stream) {
  const float* x      = (const float*)d_in[0];
  const float* nv1    = (const float*)d_in[1];
  const float* nv2    = (const float*)d_in[2];
  const float* w_st   = (const float*)d_in[3];
  const float* b_st   = (const float*)d_in[4];
  const float* w_mlp  = (const float*)d_in[5];
  const float* b_mlp  = (const float*)d_in[6];
  const float* w_end  = (const float*)d_in[7];
  const float* b_end  = (const float*)d_in[8];
  const float* w_lin  = (const float*)d_in[9];
  const float* b_lin  = (const float*)d_in[10];
  const float* ln_g   = (const float*)d_in[11];
  const float* ln_b   = (const float*)d_in[12];

  char* ws = (char*)d_ws;
  const size_t SZ_A = (size_t)DM * DM * 2;    // 8 MB
  const size_t SZ_H = (size_t)4096 * DM * 2;  // 16 MB
  unsigned short* Ab    = (unsigned short*)(ws);
  unsigned short* H0    = (unsigned short*)(ws + SZ_A);
  unsigned short* H1    = (unsigned short*)(ws + SZ_A + SZ_H);
  unsigned short* H2    = (unsigned short*)(ws + SZ_A + 2 * SZ_H);
  unsigned short* H3    = (unsigned short*)(ws + SZ_A + 3 * SZ_H);
  unsigned short* OUT1  = (unsigned short*)(ws + SZ_A + 4 * SZ_H);           // [64][2048] used
  unsigned short* WPACK = (unsigned short*)(ws + SZ_A + 4 * SZ_H + 262144);  // 57344 B
  unsigned short* WL    = (unsigned short*)(ws + SZ_A + 4 * SZ_H + 524288);  // 8 MB
  float*          YP    = (float*)(ws + SZ_A + 4 * SZ_H + 524288 + SZ_A);    // 8x[64][2048] f32

  wpack_kernel<<<112, 256, 0, stream>>>(w_st, WPACK);
  adj_kernel<<<256, 256, 0, stream>>>(nv1, nv2, Ab);
  conv_kernel<<<dim3(32, BATCH), 256, 0, stream>>>(x, WPACK, b_st, H0);
  wlin_cvt<<<2048, 256, 0, stream>>>(w_lin, WL);

  gemm_nt<0><<<dim3(16, 32), 256, 0, stream>>>(H0, Ab, H0, (void*)H1);
  gemm_nt<0><<<dim3(16, 32), 256, 0, stream>>>(H1, Ab, H0, (void*)H2);
  gemm_nt<0><<<dim3(16, 32), 256, 0, stream>>>(H2, Ab, H0, (void*)H3);

  mlp_kernel<<<dim3(32, BATCH), 256, 0, stream>>>(H0, H1, H2, H3, w_mlp, b_mlp,
                                                  w_end, b_end, OUT1);
  gemm_nt<1><<<dim3(16, 8), 256, 0, stream>>>(OUT1, WL, (const unsigned short*)0, (void*)YP);
  ln_kernel<<<BATCH, 256, 0, stream>>>(YP, b_lin, ln_g, ln_b, (float*)d_out);
}

// Round 8
// 291.334 us; speedup vs baseline: 1.8378x; 1.0992x over previous
//
#include <hip/hip_runtime.h>

#define NODE_NUM 2000
#define DM 2048          // D_MODEL, also padded K/N
#define IN_DIM 7
#define CONV_CH 64
#define KER 49
#define BATCH 64

typedef __attribute__((ext_vector_type(8))) short bf16x8;
typedef __attribute__((ext_vector_type(4))) float f32x4;
typedef __attribute__((ext_vector_type(4))) unsigned int u32x4;

__device__ __forceinline__ float bf2f(unsigned short u) {
  union { unsigned int i; float f; } c; c.i = ((unsigned int)u) << 16; return c.f;
}
__device__ __forceinline__ unsigned short f2bf(float f) {
  union { float f; unsigned int i; } c; c.f = f;
  unsigned int r = c.i + 0x7FFFu + ((c.i >> 16) & 1u);
  return (unsigned short)(r >> 16);
}

// ---------------------------------------------------------------------------
// Adjacency: a[v][w] = (softmax_w(relu(nv1[v]·nv2[:,w])) + (v==w)) / 2
// ---------------------------------------------------------------------------
__global__ __launch_bounds__(256) void adj_kernel(const float* __restrict__ nv1,
                                                  const float* __restrict__ nv2,
                                                  unsigned short* __restrict__ Ab) {
  const int bid = blockIdx.x;
  const int tid = threadIdx.x;
  if (bid >= 250) {  // zero pad rows 2000..2047
    const int r0 = 2000 + (bid - 250) * 8;
    for (int i = tid; i < 8 * 2048; i += 256)
      Ab[(size_t)(r0 + (i >> 11)) * DM + (i & 2047)] = 0;
    return;
  }
  const int v0 = bid * 8;
  __shared__ float e1s[8][40];
  __shared__ float redm[8][4], redsum[8][4];
  for (int i = tid; i < 320; i += 256) e1s[i / 40][i % 40] = nv1[(v0 + i / 40) * 40 + i % 40];
  __syncthreads();
  float acc[8][8] = {};
  for (int k = 0; k < 40; ++k) {
    float xv[8];
#pragma unroll
    for (int i = 0; i < 8; ++i) {
      const int w = i * 256 + tid;
      xv[i] = (w < NODE_NUM) ? nv2[k * NODE_NUM + w] : 0.f;
    }
#pragma unroll
    for (int v = 0; v < 8; ++v) {
      const float e = e1s[v][k];
#pragma unroll
      for (int i = 0; i < 8; ++i) acc[v][i] = fmaf(e, xv[i], acc[v][i]);
    }
  }
  const int wid = tid >> 6, lane = tid & 63;
#pragma unroll
  for (int v = 0; v < 8; ++v) {
    float mx = 0.f;
#pragma unroll
    for (int i = 0; i < 8; ++i) {
      const int w = i * 256 + tid;
      const float s = (w < NODE_NUM) ? fmaxf(acc[v][i], 0.f) : -1e30f;
      acc[v][i] = s; mx = fmaxf(mx, s);
    }
    for (int o = 32; o; o >>= 1) mx = fmaxf(mx, __shfl_xor(mx, o));
    if (lane == 0) redm[v][wid] = mx;
  }
  __syncthreads();
#pragma unroll
  for (int v = 0; v < 8; ++v) {
    const float mx = fmaxf(fmaxf(redm[v][0], redm[v][1]), fmaxf(redm[v][2], redm[v][3]));
    float sum = 0.f;
#pragma unroll
    for (int i = 0; i < 8; ++i) { const float e = __expf(acc[v][i] - mx); acc[v][i] = e; sum += e; }
    for (int o = 32; o; o >>= 1) sum += __shfl_xor(sum, o);
    if (lane == 0) redsum[v][wid] = sum;
  }
  __syncthreads();
#pragma unroll
  for (int v = 0; v < 8; ++v) {
    const float sum = redsum[v][0] + redsum[v][1] + redsum[v][2] + redsum[v][3];
    const float inv = 0.5f / sum;
    const int vg = v0 + v;
#pragma unroll
    for (int i = 0; i < 8; ++i) {
      const int w = i * 256 + tid;
      const float val = acc[v][i] * inv + ((w == vg) ? 0.5f : 0.f);
      Ab[(size_t)vg * DM + w] = f2bf(val);
    }
  }
}

// ---------------------------------------------------------------------------
// Pack conv weights into per-lane MFMA A-fragment order (bf16).
// kern >= 49 -> 0  (this zero-padding is what makes garbage B-values safe)
// ---------------------------------------------------------------------------
__global__ __launch_bounds__(256) void wpack_kernel(const float* __restrict__ wst,
                                                    unsigned short* __restrict__ wpack) {
  const int idx = blockIdx.x * 256 + threadIdx.x;   // 112 blocks
  const int e = idx & 7;
  const int lane = (idx >> 3) & 63;
  const int w = (idx >> 9) & 3;
  const int kstep = idx >> 11;
  const int c = w * 16 + (lane & 15);
  const int k = kstep * 32 + (lane >> 4) * 8 + e;
  const int ci = k >> 6, kern = k & 63;
  const float val = (kern < KER) ? wst[(c * IN_DIM + ci) * KER + kern] : 0.f;
  wpack[idx] = f2bf(val);
}

// ---------------------------------------------------------------------------
// Start conv via MFMA, no materialized im2col: x staged as 8 shift-replicated
// bf16 copies (xcopy[s][ci][j] = x[ci][n0+j+s], 14 KB). Any 8-consecutive
// window = one aligned ds_read_b128 (copy s = q&7). B-values at kern>=49 are
// garbage but multiply zero weights. Weights A-frags in VGPRs (wpack).
// ---------------------------------------------------------------------------
__global__ __launch_bounds__(256) void conv_kernel(const float* __restrict__ x,
                                                   const unsigned short* __restrict__ wpack,
                                                   const float* __restrict__ bst,
                                                   unsigned short* __restrict__ H0) {
  __shared__ alignas(16) unsigned short xcopy[8 * 7 * 128];  // 14336 B
  const int b = blockIdx.y;
  const int n0 = blockIdx.x * 64;
  const int tid = threadIdx.x;
  const int wv = tid >> 6, lane = tid & 63;
  const int l15 = lane & 15, kg = lane >> 4;
  // A-fragments: 14 coalesced 16B loads per lane (weights stay in VGPRs)
  bf16x8 af[14];
#pragma unroll
  for (int ks = 0; ks < 14; ++ks)
    af[ks] = *(const bf16x8*)(wpack + ((size_t)(ks * 4 + wv) * 64 + lane) * 8);
  // bias -> acc init: c = wv*16 + kg*4 + r
  f32x4 acc[4];
  {
    const f32x4 bv = *(const f32x4*)(bst + wv * 16 + kg * 4);
#pragma unroll
    for (int nf = 0; nf < 4; ++nf) acc[nf] = bv;
  }
  // stage shift-replicated copies: row = s*7+ci (56 rows x 128 j), 2 j per thread
  const size_t xb = (size_t)b * (IN_DIM * DM);
#pragma unroll
  for (int it = 0; it < 14; ++it) {
    const int row = it * 4 + (tid >> 6);       // 0..55
    const int s = row / 7, ci = row % 7;
    const int j = (tid & 63) * 2;
    int g0 = n0 + j + s;     if (g0 > DM - 1) g0 = DM - 1;
    int g1 = n0 + j + 1 + s; if (g1 > DM - 1) g1 = DM - 1;
    const float v0 = x[xb + ci * DM + g0];
    const float v1 = x[xb + ci * DM + g1];
    const unsigned int pk = (unsigned int)f2bf(v0) | ((unsigned int)f2bf(v1) << 16);
    *(unsigned int*)((char*)xcopy + row * 256 + j * 2) = pk;
  }
  __syncthreads();
  // MFMA main loop: fragment (ks,nf) -> q = nf*16+l15+kern0, copy s=q&7
#pragma unroll
  for (int ks = 0; ks < 14; ++ks) {
    const int ci = ks >> 1;
    const int kern0 = ((ks & 1) << 5) + kg * 8;
#pragma unroll
    for (int nf = 0; nf < 4; ++nf) {
      const int q = nf * 16 + l15 + kern0;
      const int byte = ((q & 7) * 7 + ci) * 256 + (q & ~7) * 2;
      const bf16x8 bfr = *(const bf16x8*)((const char*)xcopy + byte);
      acc[nf] = __builtin_amdgcn_mfma_f32_16x16x32_bf16(af[ks], bfr, acc[nf], 0, 0, 0);
    }
  }
  // epilogue: c = wv*16 + kg*4 + r, n = n0 + nf*16 + l15
#pragma unroll
  for (int nf = 0; nf < 4; ++nf) {
#pragma unroll
    for (int r = 0; r < 4; ++r) {
      const int c = wv * 16 + kg * 4 + r;
      const int n = n0 + nf * 16 + l15;
      H0[(size_t)(b * 64 + c) * DM + n] =
          (n < NODE_NUM) ? f2bf(acc[nf][r]) : (unsigned short)0;
    }
  }
}

// ---------------------------------------------------------------------------
// NT-GEMM: C[m][n] = sum_k A[m][k] * Bt[n][k], lda=ldb=ldc=2048.
// Depth-2 counted-vmcnt pipeline (T3/T4): dbuf LDS, STAGE(t+2) in flight,
// vmcnt(8) waits only the older tile's 8 loads; raw barriers (no full drain).
// MODE 0: full K, mixprop epilogue  out = bf16(0.05*H0 + 0.95*acc)
// MODE 1: split-K (blockIdx.y = split of 256 k's), m0=0, f32 partial out
// ---------------------------------------------------------------------------
template <int MODE>
__global__ __launch_bounds__(256) void gemm_nt(const unsigned short* __restrict__ A,
                                               const unsigned short* __restrict__ Bt,
                                               const unsigned short* __restrict__ H0,
                                               void* __restrict__ Cout) {
  __shared__ alignas(16) unsigned short As[2][128 * 64];
  __shared__ alignas(16) unsigned short Bs[2][128 * 64];
  const int tid = threadIdx.x;
  const int n0 = blockIdx.x * 128;
  const int m0 = (MODE == 0) ? blockIdx.y * 128 : 0;
  const int kbeg = (MODE == 0) ? 0 : blockIdx.y * 256;
  const int nt = (MODE == 0) ? (DM / 64) : 4;   // always >= 2
  const int wid = tid >> 6, lane = tid & 63;
  const int wr = wid >> 1, wc = wid & 1;
  const int l15 = lane & 15, kg = lane >> 4;

  auto STAGE = [&](int buf, int k0) {
#pragma unroll
    for (int it = 0; it < 4; ++it) {
      const int lin = it * 4096 + tid * 16;
      const int row = lin >> 7;
      const int blog = (lin & 127) ^ ((row & 7) << 4);   // inverse swizzle -> logical
      const char* sa = (const char*)A + ((size_t)(m0 + row) * DM + k0) * 2 + blog;
      const char* sb = (const char*)Bt + ((size_t)(n0 + row) * DM + k0) * 2 + blog;
      __builtin_amdgcn_global_load_lds((const __attribute__((address_space(1))) void*)sa,
                                       (__attribute__((address_space(3))) void*)((char*)As[buf] + lin),
                                       16, 0, 0);
      __builtin_amdgcn_global_load_lds((const __attribute__((address_space(1))) void*)sb,
                                       (__attribute__((address_space(3))) void*)((char*)Bs[buf] + lin),
                                       16, 0, 0);
    }
  };

  f32x4 acc[4][4] = {};
  STAGE(0, kbeg);
  STAGE(1, kbeg + 64);

  for (int t = 0; t < nt; ++t) {
    const int cur = t & 1;
    // wait for tile t (the 8 oldest of up to 16 outstanding loads)
    if (t + 1 < nt) asm volatile("s_waitcnt vmcnt(8)" ::: "memory");
    else            asm volatile("s_waitcnt vmcnt(0)" ::: "memory");
    __builtin_amdgcn_s_barrier();            // all waves: tile t resident
    __builtin_amdgcn_sched_barrier(0);
    bf16x8 af[2][4], bfr[2][4];
#pragma unroll
    for (int f = 0; f < 4; ++f) {
      const int ra = wr * 64 + f * 16 + l15;
      const int rb = wc * 64 + f * 16 + l15;
#pragma unroll
      for (int kk = 0; kk < 2; ++kk) {
        const int off = kk * 64 + kg * 16;
        af[kk][f]  = *(const bf16x8*)((const char*)As[cur] + ra * 128 + (off ^ ((ra & 7) << 4)));
        bfr[kk][f] = *(const bf16x8*)((const char*)Bs[cur] + rb * 128 + (off ^ ((rb & 7) << 4)));
      }
    }
    asm volatile("s_waitcnt lgkmcnt(0)" ::: "memory");  // this wave's reads landed
    __builtin_amdgcn_sched_barrier(0);
    __builtin_amdgcn_s_barrier();            // all waves done reading buf[cur]
    __builtin_amdgcn_sched_barrier(0);
    if (t + 2 < nt) STAGE(cur, kbeg + (t + 2) * 64);    // overwrite is now safe
#pragma unroll
    for (int kk = 0; kk < 2; ++kk)
#pragma unroll
      for (int mf = 0; mf < 4; ++mf)
#pragma unroll
        for (int nf = 0; nf < 4; ++nf)
          acc[mf][nf] = __builtin_amdgcn_mfma_f32_16x16x32_bf16(af[kk][mf], bfr[kk][nf],
                                                                acc[mf][nf], 0, 0, 0);
  }
  const int l4 = lane >> 4;
#pragma unroll
  for (int mf = 0; mf < 4; ++mf) {
#pragma unroll
    for (int nf = 0; nf < 4; ++nf) {
#pragma unroll
      for (int r = 0; r < 4; ++r) {
        const int gm = m0 + wr * 64 + mf * 16 + l4 * 4 + r;
        const int gn = n0 + wc * 64 + nf * 16 + l15;
        if (MODE == 0) {
          const float v = 0.05f * bf2f(H0[(size_t)gm * DM + gn]) + 0.95f * acc[mf][nf][r];
          ((unsigned short*)Cout)[(size_t)gm * DM + gn] = f2bf(v);
        } else {
          if (gm < 64)
            ((float*)Cout)[(size_t)blockIdx.y * 64 * DM + (size_t)gm * DM + gn] = acc[mf][nf][r];
        }
      }
    }
  }
}

// ---------------------------------------------------------------------------
// MLP via MFMA (round-1 verified structure).
// ---------------------------------------------------------------------------
__global__ __launch_bounds__(256) void mlp_kernel(const unsigned short* __restrict__ h0,
                                                  const unsigned short* __restrict__ h1,
                                                  const unsigned short* __restrict__ h2,
                                                  const unsigned short* __restrict__ h3,
                                                  const float* __restrict__ wm,
                                                  const float* __restrict__ bm,
                                                  const float* __restrict__ we,
                                                  const float* __restrict__ be,
                                                  unsigned short* __restrict__ out1) {
  __shared__ alignas(16) unsigned short hs[64 * 264];  // [n][c], 528B row stride
  __shared__ alignas(16) unsigned short wl[64 * 264];  // [o][c]
  __shared__ float cbuf[128];                          // bm | we
  const int b = blockIdx.y;
  const int gn0 = blockIdx.x * 64;
  const int tid = threadIdx.x;
  for (int idx = tid; idx < 16384; idx += 256) {
    const int o = idx >> 8, c = idx & 255;
    wl[o * 264 + c] = f2bf(wm[o * 256 + c]);
  }
  if (tid < 64) cbuf[tid] = bm[tid];
  else if (tid < 128) cbuf[tid] = we[tid - 64];
  char* hsb = (char*)hs;
#pragma unroll
  for (int it = 0; it < 8; ++it) {
    const int idx = it * 256 + tid;
    const int cf = idx >> 3, n0 = (idx & 7) * 8;
    const int hop = cf >> 6, c = cf & 63;
    const unsigned short* hb = (hop == 0) ? h0 : (hop == 1) ? h1 : (hop == 2) ? h2 : h3;
    const unsigned long long* p =
        (const unsigned long long*)(hb + (size_t)(b * 64 + c) * DM + gn0 + n0);
    const unsigned long long lo = p[0], hi = p[1];
#pragma unroll
    for (int t = 0; t < 8; ++t) {
      const int i = (t + tid) & 7;
      const unsigned short val = (unsigned short)(((i & 4) ? hi : lo) >> ((i & 3) * 16));
      *(unsigned short*)(hsb + (n0 + i) * 528 + cf * 2) = val;
    }
  }
  __syncthreads();
  const int wid = tid >> 6, lane = tid & 63;
  const int l15 = lane & 15, kg = lane >> 4;
  const char* wb = (const char*)wl;
  f32x4 acc[4] = {};
#pragma unroll
  for (int kk = 0; kk < 8; ++kk) {
    const int koff = kk * 64 + kg * 16;
    const bf16x8 bfr = *(const bf16x8*)(hsb + (wid * 16 + l15) * 528 + koff);
#pragma unroll
    for (int mf = 0; mf < 4; ++mf) {
      const bf16x8 af = *(const bf16x8*)(wb + (mf * 16 + l15) * 528 + koff);
      acc[mf] = __builtin_amdgcn_mfma_f32_16x16x32_bf16(af, bfr, acc[mf], 0, 0, 0);
    }
  }
  float pl = 0.f;
#pragma unroll
  for (int mf = 0; mf < 4; ++mf) {
#pragma unroll
    for (int r = 0; r < 4; ++r) {
      const int o = mf * 16 + kg * 4 + r;
      const float s = acc[mf][r] + cbuf[o];
      const float g = 0.5f * s * (1.f + erff(s * 0.70710678118f));
      pl += cbuf[64 + o] * g;
    }
  }
  pl += __shfl_xor(pl, 16);
  pl += __shfl_xor(pl, 32);
  if (kg == 0) {
    const int n = gn0 + wid * 16 + l15;
    out1[(size_t)b * DM + n] = (n < NODE_NUM) ? f2bf(pl + be[0]) : (unsigned short)0;
  }
}

// ---------------------------------------------------------------------------
// w_lin (2048 x 2000 f32) -> bf16 [2048][2048], pad cols zeroed (vectorized)
// ---------------------------------------------------------------------------
__global__ __launch_bounds__(256) void wlin_cvt(const float* __restrict__ wlin,
                                                unsigned short* __restrict__ wl) {
  const int idx = (blockIdx.x * 256 + threadIdx.x) * 8;   // 2048 blocks
  const int d = idx >> 11, w0 = idx & 2047;
  unsigned short out[8];
#pragma unroll
  for (int j = 0; j < 8; ++j) {
    const int w = w0 + j;
    out[j] = (w < NODE_NUM) ? f2bf(wlin[d * NODE_NUM + w]) : (unsigned short)0;
  }
  *(u32x4*)(wl + idx) = *(const u32x4*)out;
}

// ---------------------------------------------------------------------------
// sum 8 split-K partials, +b_lin, LayerNorm over 2048, f32 out
// ---------------------------------------------------------------------------
__global__ __launch_bounds__(256) void ln_kernel(const float* __restrict__ yp,
                                                 const float* __restrict__ bl,
                                                 const float* __restrict__ g,
                                                 const float* __restrict__ bb,
                                                 float* __restrict__ out) {
  const int b = blockIdx.x, tid = threadIdx.x;
  __shared__ float rs[4], rq[4];
  float v[8];
  float s = 0.f;
#pragma unroll
  for (int i = 0; i < 8; ++i) {
    const int d = i * 256 + tid;
    float acc = bl[d];
#pragma unroll
    for (int sp = 0; sp < 8; ++sp) acc += yp[(size_t)sp * 64 * DM + (size_t)b * DM + d];
    v[i] = acc;
    s += acc;
  }
  for (int o = 32; o; o >>= 1) s += __shfl_xor(s, o);
  const int wid = tid >> 6, lane = tid & 63;
  if (lane == 0) rs[wid] = s;
  __syncthreads();
  s = rs[0] + rs[1] + rs[2] + rs[3];
  const float mu = s * (1.f / 2048.f);
  float q = 0.f;
#pragma unroll
  for (int i = 0; i < 8; ++i) { const float d = v[i] - mu; q += d * d; }
  for (int o = 32; o; o >>= 1) q += __shfl_xor(q, o);
  if (lane == 0) rq[wid] = q;
  __syncthreads();
  q = rq[0] + rq[1] + rq[2] + rq[3];
  const float inv = rsqrtf(q * (1.f / 2048.f) + 1e-5f);
#pragma unroll
  for (int i = 0; i < 8; ++i) {
    const int d = i * 256 + tid;
    out[(size_t)b * DM + d] = (v[i] - mu) * inv * g[d] + bb[d];
  }
}

// ---------------------------------------------------------------------------
extern "C" void kernel_launch(void* const* d_in, const int* in_sizes, int n_in,
                              void* d_out, int out_size, void* d_ws, size_t ws_size,
                              hipStream_t stream) {
  const float* x      = (const float*)d_in[0];
  const float* nv1    = (const float*)d_in[1];
  const float* nv2    = (const float*)d_in[2];
  const float* w_st   = (const float*)d_in[3];
  const float* b_st   = (const float*)d_in[4];
  const float* w_mlp  = (const float*)d_in[5];
  const float* b_mlp  = (const float*)d_in[6];
  const float* w_end  = (const float*)d_in[7];
  const float* b_end  = (const float*)d_in[8];
  const float* w_lin  = (const float*)d_in[9];
  const float* b_lin  = (const float*)d_in[10];
  const float* ln_g   = (const float*)d_in[11];
  const float* ln_b   = (const float*)d_in[12];

  char* ws = (char*)d_ws;
  const size_t SZ_A = (size_t)DM * DM * 2;    // 8 MB
  const size_t SZ_H = (size_t)4096 * DM * 2;  // 16 MB
  unsigned short* Ab    = (unsigned short*)(ws);
  unsigned short* H0    = (unsigned short*)(ws + SZ_A);
  unsigned short* H1    = (unsigned short*)(ws + SZ_A + SZ_H);
  unsigned short* H2    = (unsigned short*)(ws + SZ_A + 2 * SZ_H);
  unsigned short* H3    = (unsigned short*)(ws + SZ_A + 3 * SZ_H);
  unsigned short* OUT1  = (unsigned short*)(ws + SZ_A + 4 * SZ_H);           // [64][2048] used
  unsigned short* WPACK = (unsigned short*)(ws + SZ_A + 4 * SZ_H + 262144);  // 57344 B
  unsigned short* WL    = (unsigned short*)(ws + SZ_A + 4 * SZ_H + 524288);  // 8 MB
  float*          YP    = (float*)(ws + SZ_A + 4 * SZ_H + 524288 + SZ_A);    // 8x[64][2048] f32

  wpack_kernel<<<112, 256, 0, stream>>>(w_st, WPACK);
  adj_kernel<<<256, 256, 0, stream>>>(nv1, nv2, Ab);
  conv_kernel<<<dim3(32, BATCH), 256, 0, stream>>>(x, WPACK, b_st, H0);
  wlin_cvt<<<2048, 256, 0, stream>>>(w_lin, WL);

  gemm_nt<0><<<dim3(16, 32), 256, 0, stream>>>(H0, Ab, H0, (void*)H1);
  gemm_nt<0><<<dim3(16, 32), 256, 0, stream>>>(H1, Ab, H0, (void*)H2);
  gemm_nt<0><<<dim3(16, 32), 256, 0, stream>>>(H2, Ab, H0, (void*)H3);

  mlp_kernel<<<dim3(32, BATCH), 256, 0, stream>>>(H0, H1, H2, H3, w_mlp, b_mlp,
                                                  w_end, b_end, OUT1);
  gemm_nt<1><<<dim3(16, 8), 256, 0, stream>>>(OUT1, WL, (const unsigned short*)0, (void*)YP);
  ln_kernel<<<BATCH, 256, 0, stream>>>(YP, b_lin, ln_g, ln_b, (float*)d_out);
}

// Round 9
// 280.262 us; speedup vs baseline: 1.9104x; 1.0395x over previous
//
#include <hip/hip_runtime.h>

#define NODE_NUM 2000
#define DM 2048          // D_MODEL, also padded K/N
#define IN_DIM 7
#define CONV_CH 64
#define KER 49
#define BATCH 64

typedef __attribute__((ext_vector_type(8))) short bf16x8;
typedef __attribute__((ext_vector_type(4))) float f32x4;
typedef __attribute__((ext_vector_type(4))) unsigned int u32x4;

__device__ __forceinline__ float bf2f(unsigned short u) {
  union { unsigned int i; float f; } c; c.i = ((unsigned int)u) << 16; return c.f;
}
__device__ __forceinline__ unsigned short f2bf(float f) {
  union { float f; unsigned int i; } c; c.f = f;
  unsigned int r = c.i + 0x7FFFu + ((c.i >> 16) & 1u);
  return (unsigned short)(r >> 16);
}

// ---------------------------------------------------------------------------
// Adjacency: a[v][w] = (softmax_w(relu(nv1[v]·nv2[:,w])) + (v==w)) / 2
// ---------------------------------------------------------------------------
__global__ __launch_bounds__(256) void adj_kernel(const float* __restrict__ nv1,
                                                  const float* __restrict__ nv2,
                                                  unsigned short* __restrict__ Ab) {
  const int bid = blockIdx.x;
  const int tid = threadIdx.x;
  if (bid >= 250) {  // zero pad rows 2000..2047
    const int r0 = 2000 + (bid - 250) * 8;
    for (int i = tid; i < 8 * 2048; i += 256)
      Ab[(size_t)(r0 + (i >> 11)) * DM + (i & 2047)] = 0;
    return;
  }
  const int v0 = bid * 8;
  __shared__ float e1s[8][40];
  __shared__ float redm[8][4], redsum[8][4];
  for (int i = tid; i < 320; i += 256) e1s[i / 40][i % 40] = nv1[(v0 + i / 40) * 40 + i % 40];
  __syncthreads();
  float acc[8][8] = {};
  for (int k = 0; k < 40; ++k) {
    float xv[8];
#pragma unroll
    for (int i = 0; i < 8; ++i) {
      const int w = i * 256 + tid;
      xv[i] = (w < NODE_NUM) ? nv2[k * NODE_NUM + w] : 0.f;
    }
#pragma unroll
    for (int v = 0; v < 8; ++v) {
      const float e = e1s[v][k];
#pragma unroll
      for (int i = 0; i < 8; ++i) acc[v][i] = fmaf(e, xv[i], acc[v][i]);
    }
  }
  const int wid = tid >> 6, lane = tid & 63;
#pragma unroll
  for (int v = 0; v < 8; ++v) {
    float mx = 0.f;
#pragma unroll
    for (int i = 0; i < 8; ++i) {
      const int w = i * 256 + tid;
      const float s = (w < NODE_NUM) ? fmaxf(acc[v][i], 0.f) : -1e30f;
      acc[v][i] = s; mx = fmaxf(mx, s);
    }
    for (int o = 32; o; o >>= 1) mx = fmaxf(mx, __shfl_xor(mx, o));
    if (lane == 0) redm[v][wid] = mx;
  }
  __syncthreads();
#pragma unroll
  for (int v = 0; v < 8; ++v) {
    const float mx = fmaxf(fmaxf(redm[v][0], redm[v][1]), fmaxf(redm[v][2], redm[v][3]));
    float sum = 0.f;
#pragma unroll
    for (int i = 0; i < 8; ++i) { const float e = __expf(acc[v][i] - mx); acc[v][i] = e; sum += e; }
    for (int o = 32; o; o >>= 1) sum += __shfl_xor(sum, o);
    if (lane == 0) redsum[v][wid] = sum;
  }
  __syncthreads();
#pragma unroll
  for (int v = 0; v < 8; ++v) {
    const float sum = redsum[v][0] + redsum[v][1] + redsum[v][2] + redsum[v][3];
    const float inv = 0.5f / sum;
    const int vg = v0 + v;
#pragma unroll
    for (int i = 0; i < 8; ++i) {
      const int w = i * 256 + tid;
      const float val = acc[v][i] * inv + ((w == vg) ? 0.5f : 0.f);
      Ab[(size_t)vg * DM + w] = f2bf(val);
    }
  }
}

// ---------------------------------------------------------------------------
// Pack conv weights into per-lane MFMA A-fragment order (bf16).
// kern >= 49 -> 0  (this zero-padding is what makes garbage B-values safe)
// ---------------------------------------------------------------------------
__global__ __launch_bounds__(256) void wpack_kernel(const float* __restrict__ wst,
                                                    unsigned short* __restrict__ wpack) {
  const int idx = blockIdx.x * 256 + threadIdx.x;   // 112 blocks
  const int e = idx & 7;
  const int lane = (idx >> 3) & 63;
  const int w = (idx >> 9) & 3;
  const int kstep = idx >> 11;
  const int c = w * 16 + (lane & 15);
  const int k = kstep * 32 + (lane >> 4) * 8 + e;
  const int ci = k >> 6, kern = k & 63;
  const float val = (kern < KER) ? wst[(c * IN_DIM + ci) * KER + kern] : 0.f;
  wpack[idx] = f2bf(val);
}

// ---------------------------------------------------------------------------
// Pack MLP weights to bf16 once (mlp_kernel then stages them vectorized).
// ---------------------------------------------------------------------------
__global__ __launch_bounds__(256) void wmpack_kernel(const float* __restrict__ wm,
                                                     unsigned short* __restrict__ wmb) {
  const int idx = blockIdx.x * 256 + threadIdx.x;   // 64 blocks = 16384
  wmb[idx] = f2bf(wm[idx]);
}

// ---------------------------------------------------------------------------
// Start conv via MFMA, no materialized im2col: x staged as 8 shift-replicated
// bf16 copies. B-values at kern>=49 are garbage but multiply zero weights.
// ---------------------------------------------------------------------------
__global__ __launch_bounds__(256) void conv_kernel(const float* __restrict__ x,
                                                   const unsigned short* __restrict__ wpack,
                                                   const float* __restrict__ bst,
                                                   unsigned short* __restrict__ H0) {
  __shared__ alignas(16) unsigned short xcopy[8 * 7 * 128];  // 14336 B
  const int b = blockIdx.y;
  const int n0 = blockIdx.x * 64;
  const int tid = threadIdx.x;
  const int wv = tid >> 6, lane = tid & 63;
  const int l15 = lane & 15, kg = lane >> 4;
  bf16x8 af[14];
#pragma unroll
  for (int ks = 0; ks < 14; ++ks)
    af[ks] = *(const bf16x8*)(wpack + ((size_t)(ks * 4 + wv) * 64 + lane) * 8);
  f32x4 acc[4];
  {
    const f32x4 bv = *(const f32x4*)(bst + wv * 16 + kg * 4);
#pragma unroll
    for (int nf = 0; nf < 4; ++nf) acc[nf] = bv;
  }
  const size_t xb = (size_t)b * (IN_DIM * DM);
#pragma unroll
  for (int it = 0; it < 14; ++it) {
    const int row = it * 4 + (tid >> 6);       // 0..55
    const int s = row / 7, ci = row % 7;
    const int j = (tid & 63) * 2;
    int g0 = n0 + j + s;     if (g0 > DM - 1) g0 = DM - 1;
    int g1 = n0 + j + 1 + s; if (g1 > DM - 1) g1 = DM - 1;
    const float v0 = x[xb + ci * DM + g0];
    const float v1 = x[xb + ci * DM + g1];
    const unsigned int pk = (unsigned int)f2bf(v0) | ((unsigned int)f2bf(v1) << 16);
    *(unsigned int*)((char*)xcopy + row * 256 + j * 2) = pk;
  }
  __syncthreads();
#pragma unroll
  for (int ks = 0; ks < 14; ++ks) {
    const int ci = ks >> 1;
    const int kern0 = ((ks & 1) << 5) + kg * 8;
#pragma unroll
    for (int nf = 0; nf < 4; ++nf) {
      const int q = nf * 16 + l15 + kern0;
      const int byte = ((q & 7) * 7 + ci) * 256 + (q & ~7) * 2;
      const bf16x8 bfr = *(const bf16x8*)((const char*)xcopy + byte);
      acc[nf] = __builtin_amdgcn_mfma_f32_16x16x32_bf16(af[ks], bfr, acc[nf], 0, 0, 0);
    }
  }
#pragma unroll
  for (int nf = 0; nf < 4; ++nf) {
#pragma unroll
    for (int r = 0; r < 4; ++r) {
      const int c = wv * 16 + kg * 4 + r;
      const int n = n0 + nf * 16 + l15;
      H0[(size_t)(b * 64 + c) * DM + n] =
          (n < NODE_NUM) ? f2bf(acc[nf][r]) : (unsigned short)0;
    }
  }
}

// ---------------------------------------------------------------------------
// NT-GEMM: C[m][n] = sum_k A[m][k] * Bt[n][k], lda=ldb=ldc=2048.
// Depth-2 counted-vmcnt pipeline + XCD-aware bijective tile swizzle (T1).
// MODE 0: full K, mixprop epilogue  out = bf16(0.05*H0 + 0.95*acc)
// MODE 1: split-K (blockIdx.y = split of 256 k's), m0=0, f32 partial out
// ---------------------------------------------------------------------------
template <int MODE>
__global__ __launch_bounds__(256) void gemm_nt(const unsigned short* __restrict__ A,
                                               const unsigned short* __restrict__ Bt,
                                               const unsigned short* __restrict__ H0,
                                               void* __restrict__ Cout) {
  __shared__ alignas(16) unsigned short As[2][128 * 64];
  __shared__ alignas(16) unsigned short Bs[2][128 * 64];
  const int tid = threadIdx.x;
  int bx, by;
  if (MODE == 0) {
    // T1: nwg=512, 512%8==0 -> each XCD gets 64 contiguous logical tiles
    // (4 A-panels = 2 MB, fits per-XCD L2; B streams)
    const int lin = blockIdx.y * 16 + blockIdx.x;
    const int swz = (lin & 7) * 64 + (lin >> 3);
    bx = swz & 15;  by = swz >> 4;
  } else {
    bx = blockIdx.x;  by = blockIdx.y;
  }
  const int n0 = bx * 128;
  const int m0 = (MODE == 0) ? by * 128 : 0;
  const int kbeg = (MODE == 0) ? 0 : by * 256;
  const int nt = (MODE == 0) ? (DM / 64) : 4;   // always >= 2
  const int wid = tid >> 6, lane = tid & 63;
  const int wr = wid >> 1, wc = wid & 1;
  const int l15 = lane & 15, kg = lane >> 4;

  auto STAGE = [&](int buf, int k0) {
#pragma unroll
    for (int it = 0; it < 4; ++it) {
      const int lin = it * 4096 + tid * 16;
      const int row = lin >> 7;
      const int blog = (lin & 127) ^ ((row & 7) << 4);   // inverse swizzle -> logical
      const char* sa = (const char*)A + ((size_t)(m0 + row) * DM + k0) * 2 + blog;
      const char* sb = (const char*)Bt + ((size_t)(n0 + row) * DM + k0) * 2 + blog;
      __builtin_amdgcn_global_load_lds((const __attribute__((address_space(1))) void*)sa,
                                       (__attribute__((address_space(3))) void*)((char*)As[buf] + lin),
                                       16, 0, 0);
      __builtin_amdgcn_global_load_lds((const __attribute__((address_space(1))) void*)sb,
                                       (__attribute__((address_space(3))) void*)((char*)Bs[buf] + lin),
                                       16, 0, 0);
    }
  };

  f32x4 acc[4][4] = {};
  STAGE(0, kbeg);
  STAGE(1, kbeg + 64);

  for (int t = 0; t < nt; ++t) {
    const int cur = t & 1;
    // wait for tile t (the 8 oldest of up to 16 outstanding loads)
    if (t + 1 < nt) asm volatile("s_waitcnt vmcnt(8)" ::: "memory");
    else            asm volatile("s_waitcnt vmcnt(0)" ::: "memory");
    __builtin_amdgcn_s_barrier();            // all waves: tile t resident
    __builtin_amdgcn_sched_barrier(0);
    bf16x8 af[2][4], bfr[2][4];
#pragma unroll
    for (int f = 0; f < 4; ++f) {
      const int ra = wr * 64 + f * 16 + l15;
      const int rb = wc * 64 + f * 16 + l15;
#pragma unroll
      for (int kk = 0; kk < 2; ++kk) {
        const int off = kk * 64 + kg * 16;
        af[kk][f]  = *(const bf16x8*)((const char*)As[cur] + ra * 128 + (off ^ ((ra & 7) << 4)));
        bfr[kk][f] = *(const bf16x8*)((const char*)Bs[cur] + rb * 128 + (off ^ ((rb & 7) << 4)));
      }
    }
    asm volatile("s_waitcnt lgkmcnt(0)" ::: "memory");  // this wave's reads landed
    __builtin_amdgcn_sched_barrier(0);
    __builtin_amdgcn_s_barrier();            // all waves done reading buf[cur]
    __builtin_amdgcn_sched_barrier(0);
    if (t + 2 < nt) STAGE(cur, kbeg + (t + 2) * 64);    // overwrite is now safe
#pragma unroll
    for (int kk = 0; kk < 2; ++kk)
#pragma unroll
      for (int mf = 0; mf < 4; ++mf)
#pragma unroll
        for (int nf = 0; nf < 4; ++nf)
          acc[mf][nf] = __builtin_amdgcn_mfma_f32_16x16x32_bf16(af[kk][mf], bfr[kk][nf],
                                                                acc[mf][nf], 0, 0, 0);
  }
  const int l4 = lane >> 4;
#pragma unroll
  for (int mf = 0; mf < 4; ++mf) {
#pragma unroll
    for (int nf = 0; nf < 4; ++nf) {
#pragma unroll
      for (int r = 0; r < 4; ++r) {
        const int gm = m0 + wr * 64 + mf * 16 + l4 * 4 + r;
        const int gn = n0 + wc * 64 + nf * 16 + l15;
        if (MODE == 0) {
          const float v = 0.05f * bf2f(H0[(size_t)gm * DM + gn]) + 0.95f * acc[mf][nf][r];
          ((unsigned short*)Cout)[(size_t)gm * DM + gn] = f2bf(v);
        } else {
          if (gm < 64)
            ((float*)Cout)[(size_t)blockIdx.y * 64 * DM + (size_t)gm * DM + gn] = acc[mf][nf][r];
        }
      }
    }
  }
}

// ---------------------------------------------------------------------------
// MLP via MFMA. Weights now staged from pre-packed bf16 via b128 (was 64
// scalar f32 loads + 64 scalar ds_writes per thread).
// ---------------------------------------------------------------------------
__global__ __launch_bounds__(256) void mlp_kernel(const unsigned short* __restrict__ h0,
                                                  const unsigned short* __restrict__ h1,
                                                  const unsigned short* __restrict__ h2,
                                                  const unsigned short* __restrict__ h3,
                                                  const unsigned short* __restrict__ wmb,
                                                  const float* __restrict__ bm,
                                                  const float* __restrict__ we,
                                                  const float* __restrict__ be,
                                                  unsigned short* __restrict__ out1) {
  __shared__ alignas(16) unsigned short hs[64 * 264];  // [n][c], 528B row stride
  __shared__ alignas(16) unsigned short wl[64 * 264];  // [o][c]
  __shared__ float cbuf[128];                          // bm | we
  const int b = blockIdx.y;
  const int gn0 = blockIdx.x * 64;
  const int tid = threadIdx.x;
  // stage weights: 2048 chunks of 8 bf16, fully vectorized
#pragma unroll
  for (int it = 0; it < 8; ++it) {
    const int idx = it * 256 + tid;
    const int o = idx >> 5, c = (idx & 31) * 8;
    *(bf16x8*)&wl[o * 264 + c] = *(const bf16x8*)(wmb + o * 256 + c);
  }
  if (tid < 64) cbuf[tid] = bm[tid];
  else if (tid < 128) cbuf[tid] = we[tid - 64];
  char* hsb = (char*)hs;
#pragma unroll
  for (int it = 0; it < 8; ++it) {
    const int idx = it * 256 + tid;
    const int cf = idx >> 3, n0 = (idx & 7) * 8;
    const int hop = cf >> 6, c = cf & 63;
    const unsigned short* hb = (hop == 0) ? h0 : (hop == 1) ? h1 : (hop == 2) ? h2 : h3;
    const unsigned long long* p =
        (const unsigned long long*)(hb + (size_t)(b * 64 + c) * DM + gn0 + n0);
    const unsigned long long lo = p[0], hi = p[1];
#pragma unroll
    for (int t = 0; t < 8; ++t) {
      const int i = (t + tid) & 7;
      const unsigned short val = (unsigned short)(((i & 4) ? hi : lo) >> ((i & 3) * 16));
      *(unsigned short*)(hsb + (n0 + i) * 528 + cf * 2) = val;
    }
  }
  __syncthreads();
  const int wid = tid >> 6, lane = tid & 63;
  const int l15 = lane & 15, kg = lane >> 4;
  const char* wb = (const char*)wl;
  f32x4 acc[4] = {};
#pragma unroll
  for (int kk = 0; kk < 8; ++kk) {
    const int koff = kk * 64 + kg * 16;
    const bf16x8 bfr = *(const bf16x8*)(hsb + (wid * 16 + l15) * 528 + koff);
#pragma unroll
    for (int mf = 0; mf < 4; ++mf) {
      const bf16x8 af = *(const bf16x8*)(wb + (mf * 16 + l15) * 528 + koff);
      acc[mf] = __builtin_amdgcn_mfma_f32_16x16x32_bf16(af, bfr, acc[mf], 0, 0, 0);
    }
  }
  float pl = 0.f;
#pragma unroll
  for (int mf = 0; mf < 4; ++mf) {
#pragma unroll
    for (int r = 0; r < 4; ++r) {
      const int o = mf * 16 + kg * 4 + r;
      const float s = acc[mf][r] + cbuf[o];
      const float g = 0.5f * s * (1.f + erff(s * 0.70710678118f));
      pl += cbuf[64 + o] * g;
    }
  }
  pl += __shfl_xor(pl, 16);
  pl += __shfl_xor(pl, 32);
  if (kg == 0) {
    const int n = gn0 + wid * 16 + l15;
    out1[(size_t)b * DM + n] = (n < NODE_NUM) ? f2bf(pl + be[0]) : (unsigned short)0;
  }
}

// ---------------------------------------------------------------------------
// w_lin (2048 x 2000 f32) -> bf16 [2048][2048], pad cols zeroed (vectorized)
// ---------------------------------------------------------------------------
__global__ __launch_bounds__(256) void wlin_cvt(const float* __restrict__ wlin,
                                                unsigned short* __restrict__ wl) {
  const int idx = (blockIdx.x * 256 + threadIdx.x) * 8;   // 2048 blocks
  const int d = idx >> 11, w0 = idx & 2047;
  unsigned short out[8];
#pragma unroll
  for (int j = 0; j < 8; ++j) {
    const int w = w0 + j;
    out[j] = (w < NODE_NUM) ? f2bf(wlin[d * NODE_NUM + w]) : (unsigned short)0;
  }
  *(u32x4*)(wl + idx) = *(const u32x4*)out;
}

// ---------------------------------------------------------------------------
// sum 8 split-K partials, +b_lin, LayerNorm over 2048, f32 out
// ---------------------------------------------------------------------------
__global__ __launch_bounds__(256) void ln_kernel(const float* __restrict__ yp,
                                                 const float* __restrict__ bl,
                                                 const float* __restrict__ g,
                                                 const float* __restrict__ bb,
                                                 float* __restrict__ out) {
  const int b = blockIdx.x, tid = threadIdx.x;
  __shared__ float rs[4], rq[4];
  float v[8];
  float s = 0.f;
#pragma unroll
  for (int i = 0; i < 8; ++i) {
    const int d = i * 256 + tid;
    float acc = bl[d];
#pragma unroll
    for (int sp = 0; sp < 8; ++sp) acc += yp[(size_t)sp * 64 * DM + (size_t)b * DM + d];
    v[i] = acc;
    s += acc;
  }
  for (int o = 32; o; o >>= 1) s += __shfl_xor(s, o);
  const int wid = tid >> 6, lane = tid & 63;
  if (lane == 0) rs[wid] = s;
  __syncthreads();
  s = rs[0] + rs[1] + rs[2] + rs[3];
  const float mu = s * (1.f / 2048.f);
  float q = 0.f;
#pragma unroll
  for (int i = 0; i < 8; ++i) { const float d = v[i] - mu; q += d * d; }
  for (int o = 32; o; o >>= 1) q += __shfl_xor(q, o);
  if (lane == 0) rq[wid] = q;
  __syncthreads();
  q = rq[0] + rq[1] + rq[2] + rq[3];
  const float inv = rsqrtf(q * (1.f / 2048.f) + 1e-5f);
#pragma unroll
  for (int i = 0; i < 8; ++i) {
    const int d = i * 256 + tid;
    out[(size_t)b * DM + d] = (v[i] - mu) * inv * g[d] + bb[d];
  }
}

// ---------------------------------------------------------------------------
extern "C" void kernel_launch(void* const* d_in, const int* in_sizes, int n_in,
                              void* d_out, int out_size, void* d_ws, size_t ws_size,
                              hipStream_t stream) {
  const float* x      = (const float*)d_in[0];
  const float* nv1    = (const float*)d_in[1];
  const float* nv2    = (const float*)d_in[2];
  const float* w_st   = (const float*)d_in[3];
  const float* b_st   = (const float*)d_in[4];
  const float* w_mlp  = (const float*)d_in[5];
  const float* b_mlp  = (const float*)d_in[6];
  const float* w_end  = (const float*)d_in[7];
  const float* b_end  = (const float*)d_in[8];
  const float* w_lin  = (const float*)d_in[9];
  const float* b_lin  = (const float*)d_in[10];
  const float* ln_g   = (const float*)d_in[11];
  const float* ln_b   = (const float*)d_in[12];

  char* ws = (char*)d_ws;
  const size_t SZ_A = (size_t)DM * DM * 2;    // 8 MB
  const size_t SZ_H = (size_t)4096 * DM * 2;  // 16 MB
  unsigned short* Ab    = (unsigned short*)(ws);
  unsigned short* H0    = (unsigned short*)(ws + SZ_A);
  unsigned short* H1    = (unsigned short*)(ws + SZ_A + SZ_H);
  unsigned short* H2    = (unsigned short*)(ws + SZ_A + 2 * SZ_H);
  unsigned short* H3    = (unsigned short*)(ws + SZ_A + 3 * SZ_H);
  unsigned short* OUT1  = (unsigned short*)(ws + SZ_A + 4 * SZ_H);           // [64][2048] used
  unsigned short* WPACK = (unsigned short*)(ws + SZ_A + 4 * SZ_H + 262144);  // 57344 B
  unsigned short* WMB   = (unsigned short*)(ws + SZ_A + 4 * SZ_H + 319488);  // 32768 B
  unsigned short* WL    = (unsigned short*)(ws + SZ_A + 4 * SZ_H + 524288);  // 8 MB
  float*          YP    = (float*)(ws + SZ_A + 4 * SZ_H + 524288 + SZ_A);    // 8x[64][2048] f32

  wpack_kernel<<<112, 256, 0, stream>>>(w_st, WPACK);
  wmpack_kernel<<<64, 256, 0, stream>>>(w_mlp, WMB);
  adj_kernel<<<256, 256, 0, stream>>>(nv1, nv2, Ab);
  conv_kernel<<<dim3(32, BATCH), 256, 0, stream>>>(x, WPACK, b_st, H0);
  wlin_cvt<<<2048, 256, 0, stream>>>(w_lin, WL);

  gemm_nt<0><<<dim3(16, 32), 256, 0, stream>>>(H0, Ab, H0, (void*)H1);
  gemm_nt<0><<<dim3(16, 32), 256, 0, stream>>>(H1, Ab, H0, (void*)H2);
  gemm_nt<0><<<dim3(16, 32), 256, 0, stream>>>(H2, Ab, H0, (void*)H3);

  mlp_kernel<<<dim3(32, BATCH), 256, 0, stream>>>(H0, H1, H2, H3, WMB, b_mlp,
                                                  w_end, b_end, OUT1);
  gemm_nt<1><<<dim3(16, 8), 256, 0, stream>>>(OUT1, WL, (const unsigned short*)0, (void*)YP);
  ln_kernel<<<BATCH, 256, 0, stream>>>(YP, b_lin, ln_g, ln_b, (float*)d_out);
}

// Round 10
// 263.727 us; speedup vs baseline: 2.0302x; 1.0627x over previous
//
#include <hip/hip_runtime.h>

#define NODE_NUM 2000
#define DM 2048          // D_MODEL, also padded K/N
#define IN_DIM 7
#define CONV_CH 64
#define KER 49
#define BATCH 64

typedef __attribute__((ext_vector_type(8))) short bf16x8;
typedef __attribute__((ext_vector_type(4))) float f32x4;
typedef __attribute__((ext_vector_type(4))) unsigned int u32x4;

__device__ __forceinline__ float bf2f(unsigned short u) {
  union { unsigned int i; float f; } c; c.i = ((unsigned int)u) << 16; return c.f;
}
__device__ __forceinline__ unsigned short f2bf(float f) {
  union { float f; unsigned int i; } c; c.f = f;
  unsigned int r = c.i + 0x7FFFu + ((c.i >> 16) & 1u);
  return (unsigned short)(r >> 16);
}

// ---------------------------------------------------------------------------
// Adjacency: a[v][w] = (softmax_w(relu(nv1[v]·nv2[:,w])) + (v==w)) / 2
// 4 rows/block (512 blocks = 2/CU), thread owns 8 CONSECUTIVE w ->
// 2x float4 loads/k-iter, k+1 prefetch double-buffer. 2000 = 250*8 exactly,
// so OOB masking is whole-thread (tids 250..255).
// ---------------------------------------------------------------------------
__global__ __launch_bounds__(256) void adj_kernel(const float* __restrict__ nv1,
                                                  const float* __restrict__ nv2,
                                                  unsigned short* __restrict__ Ab) {
  const int bid = blockIdx.x;
  const int tid = threadIdx.x;
  if (bid >= 500) {  // zero pad rows 2000..2047 (12 blocks x 4 rows)
    const int r0 = 2000 + (bid - 500) * 4;
    for (int i = tid; i < 4 * 2048; i += 256)
      Ab[(size_t)(r0 + (i >> 11)) * DM + (i & 2047)] = 0;
    return;
  }
  const int v0 = bid * 4;
  __shared__ float e1s[4][40];
  __shared__ float redm[4][4], redsum[4][4];
  for (int i = tid; i < 160; i += 256) e1s[i / 40][i % 40] = nv1[(v0 + i / 40) * 40 + i % 40];
  __syncthreads();
  const int w0 = tid * 8;
  const bool oob = (w0 >= NODE_NUM);
  const float* base = nv2 + (oob ? 0 : w0);   // clamped; results masked later
  float acc[4][8] = {};
  f32x4 xa = *(const f32x4*)(base);
  f32x4 xb = *(const f32x4*)(base + 4);
  for (int k = 0; k < 40; ++k) {
    const f32x4 ca = xa, cb = xb;
    if (k < 39) {
      xa = *(const f32x4*)(base + (k + 1) * NODE_NUM);
      xb = *(const f32x4*)(base + (k + 1) * NODE_NUM + 4);
    }
#pragma unroll
    for (int v = 0; v < 4; ++v) {
      const float e = e1s[v][k];
#pragma unroll
      for (int i = 0; i < 4; ++i) {
        acc[v][i]     = fmaf(e, ca[i], acc[v][i]);
        acc[v][i + 4] = fmaf(e, cb[i], acc[v][i + 4]);
      }
    }
  }
  const int wid = tid >> 6, lane = tid & 63;
#pragma unroll
  for (int v = 0; v < 4; ++v) {
    float mx = -1e30f;
    if (!oob) {
#pragma unroll
      for (int i = 0; i < 8; ++i) {
        acc[v][i] = fmaxf(acc[v][i], 0.f);
        mx = fmaxf(mx, acc[v][i]);
      }
    }
    for (int o = 32; o; o >>= 1) mx = fmaxf(mx, __shfl_xor(mx, o));
    if (lane == 0) redm[v][wid] = mx;
  }
  __syncthreads();
#pragma unroll
  for (int v = 0; v < 4; ++v) {
    const float mx = fmaxf(fmaxf(redm[v][0], redm[v][1]), fmaxf(redm[v][2], redm[v][3]));
    float sum = 0.f;
    if (!oob) {
#pragma unroll
      for (int i = 0; i < 8; ++i) { const float e = __expf(acc[v][i] - mx); acc[v][i] = e; sum += e; }
    }
    for (int o = 32; o; o >>= 1) sum += __shfl_xor(sum, o);
    if (lane == 0) redsum[v][wid] = sum;
  }
  __syncthreads();
#pragma unroll
  for (int v = 0; v < 4; ++v) {
    const float sum = redsum[v][0] + redsum[v][1] + redsum[v][2] + redsum[v][3];
    const float inv = 0.5f / sum;
    const int vg = v0 + v;
    unsigned short out[8];
#pragma unroll
    for (int i = 0; i < 8; ++i) {
      const float val = oob ? 0.f : (acc[v][i] * inv + ((w0 + i == vg) ? 0.5f : 0.f));
      out[i] = f2bf(val);
    }
    *(u32x4*)(Ab + (size_t)vg * DM + w0) = *(const u32x4*)out;
  }
}

// ---------------------------------------------------------------------------
// Pack conv weights into per-lane MFMA A-fragment order (bf16).
// kern >= 49 -> 0  (this zero-padding is what makes garbage B-values safe)
// ---------------------------------------------------------------------------
__global__ __launch_bounds__(256) void wpack_kernel(const float* __restrict__ wst,
                                                    unsigned short* __restrict__ wpack) {
  const int idx = blockIdx.x * 256 + threadIdx.x;   // 112 blocks
  const int e = idx & 7;
  const int lane = (idx >> 3) & 63;
  const int w = (idx >> 9) & 3;
  const int kstep = idx >> 11;
  const int c = w * 16 + (lane & 15);
  const int k = kstep * 32 + (lane >> 4) * 8 + e;
  const int ci = k >> 6, kern = k & 63;
  const float val = (kern < KER) ? wst[(c * IN_DIM + ci) * KER + kern] : 0.f;
  wpack[idx] = f2bf(val);
}

// ---------------------------------------------------------------------------
// Pack MLP weights to bf16 once (mlp_kernel then stages them vectorized).
// ---------------------------------------------------------------------------
__global__ __launch_bounds__(256) void wmpack_kernel(const float* __restrict__ wm,
                                                     unsigned short* __restrict__ wmb) {
  const int idx = blockIdx.x * 256 + threadIdx.x;   // 64 blocks = 16384
  wmb[idx] = f2bf(wm[idx]);
}

// ---------------------------------------------------------------------------
// Start conv via MFMA, no materialized im2col: x staged as 8 shift-replicated
// bf16 copies. B-values at kern>=49 are garbage but multiply zero weights.
// ---------------------------------------------------------------------------
__global__ __launch_bounds__(256) void conv_kernel(const float* __restrict__ x,
                                                   const unsigned short* __restrict__ wpack,
                                                   const float* __restrict__ bst,
                                                   unsigned short* __restrict__ H0) {
  __shared__ alignas(16) unsigned short xcopy[8 * 7 * 128];  // 14336 B
  const int b = blockIdx.y;
  const int n0 = blockIdx.x * 64;
  const int tid = threadIdx.x;
  const int wv = tid >> 6, lane = tid & 63;
  const int l15 = lane & 15, kg = lane >> 4;
  bf16x8 af[14];
#pragma unroll
  for (int ks = 0; ks < 14; ++ks)
    af[ks] = *(const bf16x8*)(wpack + ((size_t)(ks * 4 + wv) * 64 + lane) * 8);
  f32x4 acc[4];
  {
    const f32x4 bv = *(const f32x4*)(bst + wv * 16 + kg * 4);
#pragma unroll
    for (int nf = 0; nf < 4; ++nf) acc[nf] = bv;
  }
  const size_t xb = (size_t)b * (IN_DIM * DM);
#pragma unroll
  for (int it = 0; it < 14; ++it) {
    const int row = it * 4 + (tid >> 6);       // 0..55
    const int s = row / 7, ci = row % 7;
    const int j = (tid & 63) * 2;
    int g0 = n0 + j + s;     if (g0 > DM - 1) g0 = DM - 1;
    int g1 = n0 + j + 1 + s; if (g1 > DM - 1) g1 = DM - 1;
    const float v0 = x[xb + ci * DM + g0];
    const float v1 = x[xb + ci * DM + g1];
    const unsigned int pk = (unsigned int)f2bf(v0) | ((unsigned int)f2bf(v1) << 16);
    *(unsigned int*)((char*)xcopy + row * 256 + j * 2) = pk;
  }
  __syncthreads();
#pragma unroll
  for (int ks = 0; ks < 14; ++ks) {
    const int ci = ks >> 1;
    const int kern0 = ((ks & 1) << 5) + kg * 8;
#pragma unroll
    for (int nf = 0; nf < 4; ++nf) {
      const int q = nf * 16 + l15 + kern0;
      const int byte = ((q & 7) * 7 + ci) * 256 + (q & ~7) * 2;
      const bf16x8 bfr = *(const bf16x8*)((const char*)xcopy + byte);
      acc[nf] = __builtin_amdgcn_mfma_f32_16x16x32_bf16(af[ks], bfr, acc[nf], 0, 0, 0);
    }
  }
#pragma unroll
  for (int nf = 0; nf < 4; ++nf) {
#pragma unroll
    for (int r = 0; r < 4; ++r) {
      const int c = wv * 16 + kg * 4 + r;
      const int n = n0 + nf * 16 + l15;
      H0[(size_t)(b * 64 + c) * DM + n] =
          (n < NODE_NUM) ? f2bf(acc[nf][r]) : (unsigned short)0;
    }
  }
}

// ---------------------------------------------------------------------------
// NT-GEMM: C[m][n] = sum_k A[m][k] * Bt[n][k], lda=ldb=ldc=2048.
// Depth-2 counted-vmcnt pipeline + XCD-aware bijective tile swizzle (T1).
// MODE 0: full K, mixprop epilogue  out = bf16(0.05*H0 + 0.95*acc)
// MODE 1: split-K (blockIdx.y = split of 256 k's), m0=0, f32 partial out
// ---------------------------------------------------------------------------
template <int MODE>
__global__ __launch_bounds__(256) void gemm_nt(const unsigned short* __restrict__ A,
                                               const unsigned short* __restrict__ Bt,
                                               const unsigned short* __restrict__ H0,
                                               void* __restrict__ Cout) {
  __shared__ alignas(16) unsigned short As[2][128 * 64];
  __shared__ alignas(16) unsigned short Bs[2][128 * 64];
  const int tid = threadIdx.x;
  int bx, by;
  if (MODE == 0) {
    // T1: nwg=512, 512%8==0 -> each XCD gets 64 contiguous logical tiles
    const int lin = blockIdx.y * 16 + blockIdx.x;
    const int swz = (lin & 7) * 64 + (lin >> 3);
    bx = swz & 15;  by = swz >> 4;
  } else {
    bx = blockIdx.x;  by = blockIdx.y;
  }
  const int n0 = bx * 128;
  const int m0 = (MODE == 0) ? by * 128 : 0;
  const int kbeg = (MODE == 0) ? 0 : by * 256;
  const int nt = (MODE == 0) ? (DM / 64) : 4;   // always >= 2
  const int wid = tid >> 6, lane = tid & 63;
  const int wr = wid >> 1, wc = wid & 1;
  const int l15 = lane & 15, kg = lane >> 4;

  auto STAGE = [&](int buf, int k0) {
#pragma unroll
    for (int it = 0; it < 4; ++it) {
      const int lin = it * 4096 + tid * 16;
      const int row = lin >> 7;
      const int blog = (lin & 127) ^ ((row & 7) << 4);   // inverse swizzle -> logical
      const char* sa = (const char*)A + ((size_t)(m0 + row) * DM + k0) * 2 + blog;
      const char* sb = (const char*)Bt + ((size_t)(n0 + row) * DM + k0) * 2 + blog;
      __builtin_amdgcn_global_load_lds((const __attribute__((address_space(1))) void*)sa,
                                       (__attribute__((address_space(3))) void*)((char*)As[buf] + lin),
                                       16, 0, 0);
      __builtin_amdgcn_global_load_lds((const __attribute__((address_space(1))) void*)sb,
                                       (__attribute__((address_space(3))) void*)((char*)Bs[buf] + lin),
                                       16, 0, 0);
    }
  };

  f32x4 acc[4][4] = {};
  STAGE(0, kbeg);
  STAGE(1, kbeg + 64);

  for (int t = 0; t < nt; ++t) {
    const int cur = t & 1;
    if (t + 1 < nt) asm volatile("s_waitcnt vmcnt(8)" ::: "memory");
    else            asm volatile("s_waitcnt vmcnt(0)" ::: "memory");
    __builtin_amdgcn_s_barrier();
    __builtin_amdgcn_sched_barrier(0);
    bf16x8 af[2][4], bfr[2][4];
#pragma unroll
    for (int f = 0; f < 4; ++f) {
      const int ra = wr * 64 + f * 16 + l15;
      const int rb = wc * 64 + f * 16 + l15;
#pragma unroll
      for (int kk = 0; kk < 2; ++kk) {
        const int off = kk * 64 + kg * 16;
        af[kk][f]  = *(const bf16x8*)((const char*)As[cur] + ra * 128 + (off ^ ((ra & 7) << 4)));
        bfr[kk][f] = *(const bf16x8*)((const char*)Bs[cur] + rb * 128 + (off ^ ((rb & 7) << 4)));
      }
    }
    asm volatile("s_waitcnt lgkmcnt(0)" ::: "memory");
    __builtin_amdgcn_sched_barrier(0);
    __builtin_amdgcn_s_barrier();
    __builtin_amdgcn_sched_barrier(0);
    if (t + 2 < nt) STAGE(cur, kbeg + (t + 2) * 64);
#pragma unroll
    for (int kk = 0; kk < 2; ++kk)
#pragma unroll
      for (int mf = 0; mf < 4; ++mf)
#pragma unroll
        for (int nf = 0; nf < 4; ++nf)
          acc[mf][nf] = __builtin_amdgcn_mfma_f32_16x16x32_bf16(af[kk][mf], bfr[kk][nf],
                                                                acc[mf][nf], 0, 0, 0);
  }
  const int l4 = lane >> 4;
#pragma unroll
  for (int mf = 0; mf < 4; ++mf) {
#pragma unroll
    for (int nf = 0; nf < 4; ++nf) {
#pragma unroll
      for (int r = 0; r < 4; ++r) {
        const int gm = m0 + wr * 64 + mf * 16 + l4 * 4 + r;
        const int gn = n0 + wc * 64 + nf * 16 + l15;
        if (MODE == 0) {
          const float v = 0.05f * bf2f(H0[(size_t)gm * DM + gn]) + 0.95f * acc[mf][nf][r];
          ((unsigned short*)Cout)[(size_t)gm * DM + gn] = f2bf(v);
        } else {
          if (gm < 64)
            ((float*)Cout)[(size_t)blockIdx.y * 64 * DM + (size_t)gm * DM + gn] = acc[mf][nf][r];
        }
      }
    }
  }
}

// ---------------------------------------------------------------------------
// MLP via MFMA. Weights staged from pre-packed bf16 via b128.
// ---------------------------------------------------------------------------
__global__ __launch_bounds__(256) void mlp_kernel(const unsigned short* __restrict__ h0,
                                                  const unsigned short* __restrict__ h1,
                                                  const unsigned short* __restrict__ h2,
                                                  const unsigned short* __restrict__ h3,
                                                  const unsigned short* __restrict__ wmb,
                                                  const float* __restrict__ bm,
                                                  const float* __restrict__ we,
                                                  const float* __restrict__ be,
                                                  unsigned short* __restrict__ out1) {
  __shared__ alignas(16) unsigned short hs[64 * 264];  // [n][c], 528B row stride
  __shared__ alignas(16) unsigned short wl[64 * 264];  // [o][c]
  __shared__ float cbuf[128];                          // bm | we
  const int b = blockIdx.y;
  const int gn0 = blockIdx.x * 64;
  const int tid = threadIdx.x;
#pragma unroll
  for (int it = 0; it < 8; ++it) {
    const int idx = it * 256 + tid;
    const int o = idx >> 5, c = (idx & 31) * 8;
    *(bf16x8*)&wl[o * 264 + c] = *(const bf16x8*)(wmb + o * 256 + c);
  }
  if (tid < 64) cbuf[tid] = bm[tid];
  else if (tid < 128) cbuf[tid] = we[tid - 64];
  char* hsb = (char*)hs;
#pragma unroll
  for (int it = 0; it < 8; ++it) {
    const int idx = it * 256 + tid;
    const int cf = idx >> 3, n0 = (idx & 7) * 8;
    const int hop = cf >> 6, c = cf & 63;
    const unsigned short* hb = (hop == 0) ? h0 : (hop == 1) ? h1 : (hop == 2) ? h2 : h3;
    const unsigned long long* p =
        (const unsigned long long*)(hb + (size_t)(b * 64 + c) * DM + gn0 + n0);
    const unsigned long long lo = p[0], hi = p[1];
#pragma unroll
    for (int t = 0; t < 8; ++t) {
      const int i = (t + tid) & 7;
      const unsigned short val = (unsigned short)(((i & 4) ? hi : lo) >> ((i & 3) * 16));
      *(unsigned short*)(hsb + (n0 + i) * 528 + cf * 2) = val;
    }
  }
  __syncthreads();
  const int wid = tid >> 6, lane = tid & 63;
  const int l15 = lane & 15, kg = lane >> 4;
  const char* wb = (const char*)wl;
  f32x4 acc[4] = {};
#pragma unroll
  for (int kk = 0; kk < 8; ++kk) {
    const int koff = kk * 64 + kg * 16;
    const bf16x8 bfr = *(const bf16x8*)(hsb + (wid * 16 + l15) * 528 + koff);
#pragma unroll
    for (int mf = 0; mf < 4; ++mf) {
      const bf16x8 af = *(const bf16x8*)(wb + (mf * 16 + l15) * 528 + koff);
      acc[mf] = __builtin_amdgcn_mfma_f32_16x16x32_bf16(af, bfr, acc[mf], 0, 0, 0);
    }
  }
  float pl = 0.f;
#pragma unroll
  for (int mf = 0; mf < 4; ++mf) {
#pragma unroll
    for (int r = 0; r < 4; ++r) {
      const int o = mf * 16 + kg * 4 + r;
      const float s = acc[mf][r] + cbuf[o];
      const float g = 0.5f * s * (1.f + erff(s * 0.70710678118f));
      pl += cbuf[64 + o] * g;
    }
  }
  pl += __shfl_xor(pl, 16);
  pl += __shfl_xor(pl, 32);
  if (kg == 0) {
    const int n = gn0 + wid * 16 + l15;
    out1[(size_t)b * DM + n] = (n < NODE_NUM) ? f2bf(pl + be[0]) : (unsigned short)0;
  }
}

// ---------------------------------------------------------------------------
// w_lin (2048 x 2000 f32) -> bf16 [2048][2048], pad cols zeroed (vectorized)
// ---------------------------------------------------------------------------
__global__ __launch_bounds__(256) void wlin_cvt(const float* __restrict__ wlin,
                                                unsigned short* __restrict__ wl) {
  const int idx = (blockIdx.x * 256 + threadIdx.x) * 8;   // 2048 blocks
  const int d = idx >> 11, w0 = idx & 2047;
  unsigned short out[8];
#pragma unroll
  for (int j = 0; j < 8; ++j) {
    const int w = w0 + j;
    out[j] = (w < NODE_NUM) ? f2bf(wlin[d * NODE_NUM + w]) : (unsigned short)0;
  }
  *(u32x4*)(wl + idx) = *(const u32x4*)out;
}

// ---------------------------------------------------------------------------
// sum 8 split-K partials, +b_lin, LayerNorm over 2048, f32 out
// ---------------------------------------------------------------------------
__global__ __launch_bounds__(256) void ln_kernel(const float* __restrict__ yp,
                                                 const float* __restrict__ bl,
                                                 const float* __restrict__ g,
                                                 const float* __restrict__ bb,
                                                 float* __restrict__ out) {
  const int b = blockIdx.x, tid = threadIdx.x;
  __shared__ float rs[4], rq[4];
  float v[8];
  float s = 0.f;
#pragma unroll
  for (int i = 0; i < 8; ++i) {
    const int d = i * 256 + tid;
    float acc = bl[d];
#pragma unroll
    for (int sp = 0; sp < 8; ++sp) acc += yp[(size_t)sp * 64 * DM + (size_t)b * DM + d];
    v[i] = acc;
    s += acc;
  }
  for (int o = 32; o; o >>= 1) s += __shfl_xor(s, o);
  const int wid = tid >> 6, lane = tid & 63;
  if (lane == 0) rs[wid] = s;
  __syncthreads();
  s = rs[0] + rs[1] + rs[2] + rs[3];
  const float mu = s * (1.f / 2048.f);
  float q = 0.f;
#pragma unroll
  for (int i = 0; i < 8; ++i) { const float d = v[i] - mu; q += d * d; }
  for (int o = 32; o; o >>= 1) q += __shfl_xor(q, o);
  if (lane == 0) rq[wid] = q;
  __syncthreads();
  q = rq[0] + rq[1] + rq[2] + rq[3];
  const float inv = rsqrtf(q * (1.f / 2048.f) + 1e-5f);
#pragma unroll
  for (int i = 0; i < 8; ++i) {
    const int d = i * 256 + tid;
    out[(size_t)b * DM + d] = (v[i] - mu) * inv * g[d] + bb[d];
  }
}

// ---------------------------------------------------------------------------
extern "C" void kernel_launch(void* const* d_in, const int* in_sizes, int n_in,
                              void* d_out, int out_size, void* d_ws, size_t ws_size,
                              hipStream_t stream) {
  const float* x      = (const float*)d_in[0];
  const float* nv1    = (const float*)d_in[1];
  const float* nv2    = (const float*)d_in[2];
  const float* w_st   = (const float*)d_in[3];
  const float* b_st   = (const float*)d_in[4];
  const float* w_mlp  = (const float*)d_in[5];
  const float* b_mlp  = (const float*)d_in[6];
  const float* w_end  = (const float*)d_in[7];
  const float* b_end  = (const float*)d_in[8];
  const float* w_lin  = (const float*)d_in[9];
  const float* b_lin  = (const float*)d_in[10];
  const float* ln_g   = (const float*)d_in[11];
  const float* ln_b   = (const float*)d_in[12];

  char* ws = (char*)d_ws;
  const size_t SZ_A = (size_t)DM * DM * 2;    // 8 MB
  const size_t SZ_H = (size_t)4096 * DM * 2;  // 16 MB
  unsigned short* Ab    = (unsigned short*)(ws);
  unsigned short* H0    = (unsigned short*)(ws + SZ_A);
  unsigned short* H1    = (unsigned short*)(ws + SZ_A + SZ_H);
  unsigned short* H2    = (unsigned short*)(ws + SZ_A + 2 * SZ_H);
  unsigned short* H3    = (unsigned short*)(ws + SZ_A + 3 * SZ_H);
  unsigned short* OUT1  = (unsigned short*)(ws + SZ_A + 4 * SZ_H);           // [64][2048] used
  unsigned short* WPACK = (unsigned short*)(ws + SZ_A + 4 * SZ_H + 262144);  // 57344 B
  unsigned short* WMB   = (unsigned short*)(ws + SZ_A + 4 * SZ_H + 319488);  // 32768 B
  unsigned short* WL    = (unsigned short*)(ws + SZ_A + 4 * SZ_H + 524288);  // 8 MB
  float*          YP    = (float*)(ws + SZ_A + 4 * SZ_H + 524288 + SZ_A);    // 8x[64][2048] f32

  wpack_kernel<<<112, 256, 0, stream>>>(w_st, WPACK);
  wmpack_kernel<<<64, 256, 0, stream>>>(w_mlp, WMB);
  adj_kernel<<<512, 256, 0, stream>>>(nv1, nv2, Ab);
  conv_kernel<<<dim3(32, BATCH), 256, 0, stream>>>(x, WPACK, b_st, H0);
  wlin_cvt<<<2048, 256, 0, stream>>>(w_lin, WL);

  gemm_nt<0><<<dim3(16, 32), 256, 0, stream>>>(H0, Ab, H0, (void*)H1);
  gemm_nt<0><<<dim3(16, 32), 256, 0, stream>>>(H1, Ab, H0, (void*)H2);
  gemm_nt<0><<<dim3(16, 32), 256, 0, stream>>>(H2, Ab, H0, (void*)H3);

  mlp_kernel<<<dim3(32, BATCH), 256, 0, stream>>>(H0, H1, H2, H3, WMB, b_mlp,
                                                  w_end, b_end, OUT1);
  gemm_nt<1><<<dim3(16, 8), 256, 0, stream>>>(OUT1, WL, (const unsigned short*)0, (void*)YP);
  ln_kernel<<<BATCH, 256, 0, stream>>>(YP, b_lin, ln_g, ln_b, (float*)d_out);
}